// Round 5
// baseline (246.304 us; speedup 1.0000x reference)
//
#include <hip/hip_runtime.h>
#include <hip/hip_bf16.h>

// GCN 2-layer: N=50000 nodes, E=800000 edges, 256 -> 64 (relu) -> 40 (log_softmax)
// Float inputs fp32 or bf16 (device-detected); edges int32 or int64 (detected).
// agg[n] = dinv[n] * ( sum_{s in N(n)} h'[s] + h'[n] ), h' = h*dinv pre-scaled.
// CSR: hist records per-edge rank -> atomic-free fill.
// R2/R3: compiler caps in-flight gather loads (~2/wave); source-level forcing
// failed (VGPR ceiling, no spills -> depth never materialized). R4: L2-residency
// split null (misses are compulsory per-XCD, not capacity). Model candidates:
// (a) per-CU outstanding-miss cap x latency; (b) L2 random-line rate ~2/cy/XCD.
// R5: decisive depth experiment. k_gather1f stages each batch (4 nodes x 16
// neighbors = 64 rows = 8KB/wave) into LDS via 32x global_load_lds size=4
// (VGPR-free, 64 rows in flight per wave), then vmcnt(0) + ds_read_b64
// accumulate. If (a): ~2x win. If (b): null -> R6 reduces line count.

constexpr int NN   = 50000;
constexpr int NNP  = 50048;                 // padded row count (zero rows >= NN)
constexpr int ZR   = 50000;                 // zero-row index for padding lanes
constexpr int NE   = 800000;
constexpr int FEAT = 256;
constexpr int HID  = 64;
constexpr int OUTD = 40;
constexpr int NC   = (NN + 255) / 256;     // 196 scan chunks
constexpr int FCH  = 2048;                  // fill: edges per chunk
constexpr int NCH  = (NE + FCH - 1) / FCH;  // 391 chunks

typedef short bf16x8 __attribute__((ext_vector_type(8)));
typedef float f32x4  __attribute__((ext_vector_type(4)));

__device__ __forceinline__ float b2f(__hip_bfloat16 v) { return __bfloat162float(v); }
__device__ __forceinline__ float bflo(unsigned u) { return __uint_as_float(u << 16); }
__device__ __forceinline__ float bfhi(unsigned u) { return __uint_as_float(u & 0xffff0000u); }
__device__ __forceinline__ unsigned short f2bu(float f) {
    __hip_bfloat16 h = __float2bfloat16(f);
    return *(unsigned short*)&h;
}
__device__ __forceinline__ unsigned pack2bf(float a, float b) {
    return (unsigned)f2bu(a) | ((unsigned)f2bu(b) << 16);
}
__device__ __forceinline__ float loadF(const void* p, int i, bool f32) {
    return f32 ? ((const float*)p)[i] : b2f(((const __hip_bfloat16*)p)[i]);
}
__device__ __forceinline__ int loadE(const int* ei, int e, int row, bool i64) {
    long long idx = (long long)row * NE + e;
    return i64 ? ei[2 * idx] : ei[idx];
}
__device__ __forceinline__ bf16x8 pack8(float4 a, float4 b) {
    bf16x8 r;
    r[0] = (short)f2bu(a.x); r[1] = (short)f2bu(a.y);
    r[2] = (short)f2bu(a.z); r[3] = (short)f2bu(a.w);
    r[4] = (short)f2bu(b.x); r[5] = (short)f2bu(b.y);
    r[6] = (short)f2bu(b.z); r[7] = (short)f2bu(b.w);
    return r;
}
// async global->LDS, 4B/lane: lds dest = uniform base + lane*4, global per-lane
__device__ __forceinline__ void gload_lds4(const void* g, void* l) {
    __builtin_amdgcn_global_load_lds(
        (const __attribute__((address_space(1))) void*)g,
        (__attribute__((address_space(3))) void*)l, 4, 0, 0);
}

// ---- zero + dtype detection + h2 pad-row zero ------------------------------
__global__ __launch_bounds__(256) void k_zero(const unsigned* __restrict__ xw,
                                              const int* __restrict__ ew,
                                              int* flags, int* cnt,
                                              unsigned* __restrict__ h2pad) {
    int i = blockIdx.x * 256 + threadIdx.x;
    if (i < NN) cnt[i] = 0;
    if (blockIdx.x == 0 && threadIdx.x < 20) h2pad[threadIdx.x] = 0;  // h2 zero row
    if (blockIdx.x == 0 && threadIdx.x == 0) {
        int outliers = 0;
        for (int k = 0; k < 256; k++) {
            int e = (xw[k] >> 7) & 0xFF;   // exponent of low bf16 half
            if (e < 100 || e > 140) outliers++;
        }
        flags[0] = (outliers > 64) ? 1 : 0;
        int nz = 0;
        for (int k = 1; k < 64; k += 2)
            if (ew[k] != 0) nz++;
        flags[1] = (nz == 0) ? 1 : 0;
    }
}

// ---- CSR build -------------------------------------------------------------
__global__ __launch_bounds__(256) void k_hist(const int* __restrict__ ei,
                                              const int* __restrict__ flags,
                                              int* cnt, int* __restrict__ rank) {
    const bool i64 = flags[1] != 0;
    int e = blockIdx.x * 256 + threadIdx.x;
    if (e < NE) rank[e] = atomicAdd(&cnt[loadE(ei, e, 1, i64)], 1);
}
__global__ __launch_bounds__(256) void k_scan1(const int* __restrict__ cnt,
                                               int* row_start, int* partial, float* dinv) {
    __shared__ int s[256];
    int t = threadIdx.x, i = blockIdx.x * 256 + t;
    int v = (i < NN) ? cnt[i] : 0;
    if (i < NN) dinv[i] = rsqrtf(1.0f + (float)v);   // +1 self loop
    s[t] = v;
    __syncthreads();
    for (int off = 1; off < 256; off <<= 1) {
        int tmp = (t >= off) ? s[t - off] : 0;
        __syncthreads();
        s[t] += tmp;
        __syncthreads();
    }
    if (i < NN) row_start[i] = s[t] - v;       // exclusive within chunk
    if (t == 255) partial[blockIdx.x] = s[255];
}
// single block: pp[c] = exclusive prefix of partial[0..NC)
__global__ __launch_bounds__(256) void k_scan2p(const int* __restrict__ partial, int* pp) {
    __shared__ int s[256];
    int t = threadIdx.x;
    int v = (t < NC) ? partial[t] : 0;
    s[t] = v;
    __syncthreads();
    for (int off = 1; off < 256; off <<= 1) {
        int tmp = (t >= off) ? s[t - off] : 0;
        __syncthreads();
        s[t] += tmp;
        __syncthreads();
    }
    pp[t] = s[t] - v;
}
// Atomic-free fill; 8 blocks per chunk, class = dst/6250 for XCD write locality.
__global__ __launch_bounds__(256) void k_fill(const int* __restrict__ ei,
                                              const int* __restrict__ flags,
                                              const int* __restrict__ row_start,
                                              const int* __restrict__ pp,
                                              const int* __restrict__ rank,
                                              unsigned short* __restrict__ csr16) {
    const bool i64 = flags[1] != 0;
    const int cls = blockIdx.x & 7;
    const int e0 = (blockIdx.x >> 3) * FCH;
#pragma unroll
    for (int k = 0; k < FCH / 256; k++) {
        int e = e0 + k * 256 + threadIdx.x;
        if (e < NE) {
            int d = loadE(ei, e, 1, i64);
            if (d / 6250 == cls) {
                int s = loadE(ei, e, 0, i64);
                csr16[row_start[d] + pp[d >> 8] + rank[e]] = (unsigned short)s;
            }
        }
    }
}

// ---- layer 1 GEMM (MFMA): h1' = (x @ W1) * dinv[row]; zero rows >= NN ------
__global__ __launch_bounds__(256) void k_gemm1(const void* __restrict__ xb,
                                               const void* __restrict__ W1,
                                               const float* __restrict__ dinv,
                                               const int* __restrict__ flags,
                                               unsigned short* __restrict__ h1u) {
    __shared__ __align__(16) unsigned short wt16[64 * 264];
    const bool f32 = flags[0] != 0;
    const int t = threadIdx.x;
    if (f32) {
        const float* wf = (const float*)W1;
        for (int i = t * 4; i < FEAT * HID; i += 1024) {
            float4 w = *(const float4*)(wf + i);
            int k = i >> 6, n0 = i & 63;
            wt16[(n0 + 0) * 264 + k] = f2bu(w.x);
            wt16[(n0 + 1) * 264 + k] = f2bu(w.y);
            wt16[(n0 + 2) * 264 + k] = f2bu(w.z);
            wt16[(n0 + 3) * 264 + k] = f2bu(w.w);
        }
    } else {
        const unsigned short* wu = (const unsigned short*)W1;
        for (int i = t * 4; i < FEAT * HID; i += 1024) {
            ushort4 w = *(const ushort4*)(wu + i);
            int k = i >> 6, n0 = i & 63;
            wt16[(n0 + 0) * 264 + k] = w.x;
            wt16[(n0 + 1) * 264 + k] = w.y;
            wt16[(n0 + 2) * 264 + k] = w.z;
            wt16[(n0 + 3) * 264 + k] = w.w;
        }
    }
    const int wv = t >> 6, lane = t & 63, l15 = lane & 15, quad = lane >> 4;
    const int gr = blockIdx.x * 64 + wv * 16 + l15;
    const bool rowok = gr < NN;
    f32x4 acc[4];
#pragma unroll
    for (int nt = 0; nt < 4; nt++) acc[nt] = (f32x4){0.f, 0.f, 0.f, 0.f};
    __syncthreads();

    if (f32) {
        const float* xr = (const float*)xb + (size_t)gr * FEAT + quad * 8;
        float4 z4 = make_float4(0, 0, 0, 0);
        float4 c0 = rowok ? *(const float4*)xr : z4;
        float4 c1 = rowok ? *(const float4*)(xr + 4) : z4;
#pragma unroll
        for (int ks = 0; ks < 8; ks++) {
            float4 n0 = z4, n1 = z4;
            if (ks < 7 && rowok) {
                n0 = *(const float4*)(xr + (ks + 1) * 32);
                n1 = *(const float4*)(xr + (ks + 1) * 32 + 4);
            }
            bf16x8 a = pack8(c0, c1);
            const unsigned short* wk = wt16 + ks * 32 + quad * 8;
#pragma unroll
            for (int nt = 0; nt < 4; nt++) {
                bf16x8 b = *(const bf16x8*)(wk + (size_t)(nt * 16 + l15) * 264);
                acc[nt] = __builtin_amdgcn_mfma_f32_16x16x32_bf16(a, b, acc[nt], 0, 0, 0);
            }
            c0 = n0; c1 = n1;
        }
    } else {
        const unsigned short* xr = (const unsigned short*)xb + (size_t)gr * FEAT + quad * 8;
        bf16x8 zz = (bf16x8){0, 0, 0, 0, 0, 0, 0, 0};
        bf16x8 cur = rowok ? *(const bf16x8*)xr : zz;
#pragma unroll
        for (int ks = 0; ks < 8; ks++) {
            bf16x8 nxt = zz;
            if (ks < 7 && rowok) nxt = *(const bf16x8*)(xr + (ks + 1) * 32);
            const unsigned short* wk = wt16 + ks * 32 + quad * 8;
#pragma unroll
            for (int nt = 0; nt < 4; nt++) {
                bf16x8 b = *(const bf16x8*)(wk + (size_t)(nt * 16 + l15) * 264);
                acc[nt] = __builtin_amdgcn_mfma_f32_16x16x32_bf16(cur, b, acc[nt], 0, 0, 0);
            }
            cur = nxt;
        }
    }
    const int rbase = blockIdx.x * 64 + wv * 16 + quad * 4;
    float dv[4];
#pragma unroll
    for (int r = 0; r < 4; r++) dv[r] = (rbase + r < NN) ? dinv[rbase + r] : 0.f;
#pragma unroll
    for (int r = 0; r < 4; r++) {
        int grow = rbase + r;   // < NNP always (grid covers 50048 rows)
#pragma unroll
        for (int nt = 0; nt < 4; nt++)
            h1u[(size_t)grow * HID + nt * 16 + l15] = f2bu(acc[nt][r] * dv[r]);
    }
}

// ---- fused: s = sum h1'[{n}uN(n)] ; g = relu(dn*s + b1) ; h2' = dn*(g@W2) --
// R5: LDS-staged gather. Per wave per batch: 64 rows (4 nodes x 16 neighbors,
// ZR-padded) DMA'd into LDS via 32x global_load_lds size=4 (2 rows/instr,
// VGPR-free, all 64 rows in flight), then vmcnt(0) + 16x ds_read_b64/lane.
__global__ __launch_bounds__(256, 3) void k_gather1f(const uint2* __restrict__ h1v,
                                                  const float* __restrict__ dinv,
                                                  const int* __restrict__ row_start,
                                                  const int* __restrict__ pp,
                                                  const int* __restrict__ cnt,
                                                  const unsigned short* __restrict__ csr16,
                                                  const void* __restrict__ W2,
                                                  const void* __restrict__ b1,
                                                  const int* __restrict__ flags,
                                                  unsigned short* __restrict__ h2u) {
    __shared__ __align__(16) unsigned stage[4][64][32];  // 32KB: [wave][row][dword]
    __shared__ __align__(16) float w2t[OUTD * 68];   // [col][k], stride 68
    __shared__ __align__(16) float gbuf[16 * 68];    // [node][k], stride 68
    __shared__ float dns[16];
    const bool f32 = flags[0] != 0;
    const int t = threadIdx.x;
    for (int i = t; i < HID * OUTD; i += 256) {
        int c = i >> 6, k = i & 63;
        w2t[c * 68 + k] = loadF(W2, (size_t)k * OUTD + c, f32);
    }
    const int wid = t >> 6, lane = t & 63;
    const int q = lane >> 4, l16 = lane & 15;
    const int hi = lane >> 5;                // 0 for lanes 0-31, 1 for 32-63
    const int nl = t >> 4;                   // = wid*4 + q
    const int n = blockIdx.x * 16 + nl;      // < NN (grid exact)
    const float dn = dinv[n];
    const unsigned* h1d = (const unsigned*)h1v;
    uint2 u0 = h1v[n * 16 + l16];            // self row (fits int: < 800016)
    float a0 = bflo(u0.x), a1 = bfhi(u0.x), a2 = bflo(u0.y), a3 = bfhi(u0.y);
    float e0 = 0.f, e1 = 0.f, e2 = 0.f, e3 = 0.f;
    const int rs = row_start[n] + pp[n >> 8], c = cnt[n];
    int cmax = max(c, __shfl_xor(c, 16, 64));        // wave-uniform max degree
    cmax = max(cmax, __shfl_xor(cmax, 32, 64));
    for (int base = 0; base < cmax; base += 16) {
        __builtin_amdgcn_sched_barrier(0);   // keep prev batch's reads before DMAs
        int sv = (base + l16 < c) ? (int)csr16[rs + base + l16] : ZR;
        // stage 64 rows: instr i covers flat rows 2i (lanes 0-31), 2i+1 (32-63);
        // flat row k = q*16 + j  (neighbor j of wave-node q)
#pragma unroll
        for (int i = 0; i < 32; i++) {
            int s = __shfl(sv, 2 * i + hi, 64);
            gload_lds4(h1d + (((unsigned)s) << 5) + (lane & 31), &stage[wid][2 * i][0]);
        }
        asm volatile("s_waitcnt vmcnt(0)" ::: "memory");
#pragma unroll
        for (int j = 0; j < 16; j++) {
            uint2 v = *(const uint2*)&stage[wid][q * 16 + j][l16 * 2];
            if (j & 1) {
                e0 += bflo(v.x); e1 += bfhi(v.x); e2 += bflo(v.y); e3 += bfhi(v.y);
            } else {
                a0 += bflo(v.x); a1 += bfhi(v.x); a2 += bflo(v.y); a3 += bfhi(v.y);
            }
        }
    }
    int cb = 4 * l16;
    float g0 = fmaxf(dn * (a0 + e0) + loadF(b1, cb, f32), 0.f);
    float g1 = fmaxf(dn * (a1 + e1) + loadF(b1, cb + 1, f32), 0.f);
    float g2 = fmaxf(dn * (a2 + e2) + loadF(b1, cb + 2, f32), 0.f);
    float g3 = fmaxf(dn * (a3 + e3) + loadF(b1, cb + 3, f32), 0.f);
    *(float4*)(gbuf + nl * 68 + cb) = make_float4(g0, g1, g2, g3);
    if (l16 == 0) dns[nl] = dn;
    __syncthreads();
    for (int idx = t; idx < 16 * OUTD; idx += 256) {
        int node = idx / OUTD, col = idx % OUTD;
        const float4* gp = (const float4*)(gbuf + node * 68);
        const float4* wp = (const float4*)(w2t + col * 68);
        float o = 0.f;
#pragma unroll 4
        for (int k4 = 0; k4 < 16; k4++) {
            float4 a = gp[k4], b = wp[k4];
            o += a.x * b.x + a.y * b.y + a.z * b.z + a.w * b.w;
        }
        h2u[(size_t)(blockIdx.x * 16 + node) * OUTD + col] = f2bu(o * dns[node]);
    }
}

// ---- CSR gather layer 2 + bias + log_softmax (branch-free 16-deep) ---------
// UNCHANGED (in-bench control for the LDS-staging experiment).
__global__ __launch_bounds__(256, 4) void k_gather2(const uint2* __restrict__ h2v,
                                                 const float* __restrict__ dinv,
                                                 const int* __restrict__ row_start,
                                                 const int* __restrict__ pp,
                                                 const int* __restrict__ cnt,
                                                 const unsigned short* __restrict__ csr16,
                                                 const void* __restrict__ b2,
                                                 const int* __restrict__ flags,
                                                 void* __restrict__ out) {
    const bool f32 = flags[0] != 0;
    const int t = threadIdx.x;
    const int nl = t >> 4, l16 = t & 15;
    const int n = blockIdx.x * 16 + nl;      // < NN (grid exact)
    const bool act = l16 < 10;               // 10 uint2 per 40-col row
    const float dn = dinv[n];
    const int lclamp = act ? l16 : 9;        // inactive lanes read lane-9 slot (discarded)
    uint2 u0 = h2v[n * 10 + lclamp];         // fits int: < 500010
    float a0 = bflo(u0.x), a1 = bfhi(u0.x), a2 = bflo(u0.y), a3 = bfhi(u0.y);
    float e0 = 0.f, e1 = 0.f, e2 = 0.f, e3 = 0.f;
    const int rs = row_start[n] + pp[n >> 8], c = cnt[n];
    for (int base = 0; base < c; base += 16) {
        int rem = c - base;
        int sv = (l16 < rem) ? (int)csr16[rs + base + l16] : ZR;
        int s0  = __shfl(sv, 0, 16),  s1  = __shfl(sv, 1, 16);
        int s2  = __shfl(sv, 2, 16),  s3  = __shfl(sv, 3, 16);
        int s4  = __shfl(sv, 4, 16),  s5  = __shfl(sv, 5, 16);
        int s6  = __shfl(sv, 6, 16),  s7  = __shfl(sv, 7, 16);
        int s8  = __shfl(sv, 8, 16),  s9  = __shfl(sv, 9, 16);
        int s10 = __shfl(sv, 10, 16), s11 = __shfl(sv, 11, 16);
        int s12 = __shfl(sv, 12, 16), s13 = __shfl(sv, 13, 16);
        int s14 = __shfl(sv, 14, 16), s15 = __shfl(sv, 15, 16);
        uint2 b0  = h2v[s0  * 10 + lclamp], b1_ = h2v[s1  * 10 + lclamp];
        uint2 b2_ = h2v[s2  * 10 + lclamp], b3_ = h2v[s3  * 10 + lclamp];
        uint2 b4_ = h2v[s4  * 10 + lclamp], b5_ = h2v[s5  * 10 + lclamp];
        uint2 b6_ = h2v[s6  * 10 + lclamp], b7_ = h2v[s7  * 10 + lclamp];
        uint2 d0  = h2v[s8  * 10 + lclamp], d1  = h2v[s9  * 10 + lclamp];
        uint2 d2  = h2v[s10 * 10 + lclamp], d3  = h2v[s11 * 10 + lclamp];
        uint2 d4  = h2v[s12 * 10 + lclamp], d5  = h2v[s13 * 10 + lclamp];
        uint2 d6  = h2v[s14 * 10 + lclamp], d7  = h2v[s15 * 10 + lclamp];
        __builtin_amdgcn_sched_barrier(0);   // pin: all 16 loads issue first
        a0 += bflo(b0.x);  a1 += bfhi(b0.x);  a2 += bflo(b0.y);  a3 += bfhi(b0.y);
        a0 += bflo(b1_.x); a1 += bfhi(b1_.x); a2 += bflo(b1_.y); a3 += bfhi(b1_.y);
        a0 += bflo(b2_.x); a1 += bfhi(b2_.x); a2 += bflo(b2_.y); a3 += bfhi(b2_.y);
        a0 += bflo(b3_.x); a1 += bfhi(b3_.x); a2 += bflo(b3_.y); a3 += bfhi(b3_.y);
        a0 += bflo(b4_.x); a1 += bfhi(b4_.x); a2 += bflo(b4_.y); a3 += bfhi(b4_.y);
        a0 += bflo(b5_.x); a1 += bfhi(b5_.x); a2 += bflo(b5_.y); a3 += bfhi(b5_.y);
        a0 += bflo(b6_.x); a1 += bfhi(b6_.x); a2 += bflo(b6_.y); a3 += bfhi(b6_.y);
        a0 += bflo(b7_.x); a1 += bfhi(b7_.x); a2 += bflo(b7_.y); a3 += bfhi(b7_.y);
        e0 += bflo(d0.x);  e1 += bfhi(d0.x);  e2 += bflo(d0.y);  e3 += bfhi(d0.y);
        e0 += bflo(d1.x);  e1 += bfhi(d1.x);  e2 += bflo(d1.y);  e3 += bfhi(d1.y);
        e0 += bflo(d2.x);  e1 += bfhi(d2.x);  e2 += bflo(d2.y);  e3 += bfhi(d2.y);
        e0 += bflo(d3.x);  e1 += bfhi(d3.x);  e2 += bflo(d3.y);  e3 += bfhi(d3.y);
        e0 += bflo(d4.x);  e1 += bfhi(d4.x);  e2 += bflo(d4.y);  e3 += bfhi(d4.y);
        e0 += bflo(d5.x);  e1 += bfhi(d5.x);  e2 += bflo(d5.y);  e3 += bfhi(d5.y);
        e0 += bflo(d6.x);  e1 += bfhi(d6.x);  e2 += bflo(d6.y);  e3 += bfhi(d6.y);
        e0 += bflo(d7.x);  e1 += bfhi(d7.x);  e2 += bflo(d7.y);  e3 += bfhi(d7.y);
    }
    int cb = 4 * l16;
    float v0 = -3.0e38f, v1 = -3.0e38f, v2 = -3.0e38f, v3 = -3.0e38f;
    if (act) {
        v0 = dn * (a0 + e0) + loadF(b2, cb, f32);
        v1 = dn * (a1 + e1) + loadF(b2, cb + 1, f32);
        v2 = dn * (a2 + e2) + loadF(b2, cb + 2, f32);
        v3 = dn * (a3 + e3) + loadF(b2, cb + 3, f32);
    }
    float mx = fmaxf(fmaxf(v0, v1), fmaxf(v2, v3));
#pragma unroll
    for (int off = 8; off; off >>= 1) mx = fmaxf(mx, __shfl_xor(mx, off, 16));
    float ev = act ? expf(v0 - mx) + expf(v1 - mx) + expf(v2 - mx) + expf(v3 - mx) : 0.f;
#pragma unroll
    for (int off = 8; off; off >>= 1) ev += __shfl_xor(ev, off, 16);
    float lg = logf(ev);
    if (act) {
        float r0 = v0 - mx - lg, r1 = v1 - mx - lg;
        float r2 = v2 - mx - lg, r3 = v3 - mx - lg;
        if (f32) {
            *(float4*)((float*)out + (size_t)n * OUTD + cb) = make_float4(r0, r1, r2, r3);
        } else {
            ((uint2*)out)[(size_t)n * 10 + l16] = make_uint2(pack2bf(r0, r1), pack2bf(r2, r3));
        }
    }
}

extern "C" void kernel_launch(void* const* d_in, const int* in_sizes, int n_in,
                              void* d_out, int out_size, void* d_ws, size_t ws_size,
                              hipStream_t stream) {
    const void* x  = d_in[0];
    const int*  ei = (const int*)d_in[1];
    const void* W1 = d_in[2];
    const void* b1 = d_in[3];
    const void* W2 = d_in[4];
    const void* b2 = d_in[5];

    // ws layout (4-byte words):
    // flags[16] | dinv[50048] | cnt[50048] | row_start[50048] | partial[256] |
    // pp[256] | rank[800000] | csr16 ushort[800000] | h1' bf16 [NNP*64] |
    // h2' bf16 [NNP*40]   (~15.8 MB)
    float* ws        = (float*)d_ws;
    int*   flags     = (int*)ws;
    float* dinv      = ws + 16;
    int*   cnt       = (int*)(dinv + 50048);
    int*   row_start = cnt + 50048;
    int*   partial   = row_start + 50048;
    int*   pp        = partial + 256;
    int*   rank      = pp + 256;
    unsigned short* csr16 = (unsigned short*)(rank + NE);
    unsigned short* h1u   = csr16 + NE;
    unsigned short* h2u   = h1u + (size_t)NNP * HID;
    unsigned* h2pad = (unsigned*)(h2u + (size_t)ZR * OUTD);   // 20 dwords

    k_zero  <<<(NN + 255) / 256, 256, 0, stream>>>((const unsigned*)x, ei, flags, cnt, h2pad);
    k_hist  <<<(NE + 255) / 256, 256, 0, stream>>>(ei, flags, cnt, rank);
    k_scan1 <<<NC, 256, 0, stream>>>(cnt, row_start, partial, dinv);
    k_scan2p<<<1, 256, 0, stream>>>(partial, pp);
    k_fill  <<<NCH * 8, 256, 0, stream>>>(ei, flags, row_start, pp, rank, csr16);
    k_gemm1 <<<NNP / 64, 256, 0, stream>>>(x, W1, dinv, flags, h1u);
    k_gather1f<<<NN / 16, 256, 0, stream>>>((const uint2*)h1u, dinv, row_start, pp, cnt, csr16,
                                            W2, b1, flags, h2u);
    k_gather2<<<NN / 16, 256, 0, stream>>>((const uint2*)h2u, dinv, row_start, pp, cnt, csr16,
                                           b2, flags, d_out);
}

// Round 6
// 233.900 us; speedup vs baseline: 1.0530x; 1.0530x over previous
//
#include <hip/hip_runtime.h>
#include <hip/hip_bf16.h>

// GCN 2-layer: N=50000 nodes, E=800000 edges, 256 -> 64 (relu) -> 40 (log_softmax)
// Model (R0-R5): gather throughput is INVARIANT at ~40k lines/us across all
// schedules (depth 2 vs 128, occupancy 60% vs 26%) => per-CU outstanding
// line-fill cap (~30 MSHRs) x avg latency (~450cy mixed L2/L3). Levers:
// line COUNT and line LATENCY only.
// R6: (a) revert gather1f to best-known R2 form (42.5us);
// (b) h2 messages in fp8 e4m3, 64B-stride rows -> 1 line/touch (was 2) and
//     3.2MB total -> fits each XCD 4MB L2;
// (c) k_warm pre-streams h2 into all 8 XCD L2s -> gather2 at L2-hit latency.

constexpr int NN   = 50000;
constexpr int NNP  = 50048;                 // padded row count (zero rows >= NN)
constexpr int ZR   = 50000;                 // zero-row index for padding lanes
constexpr int NE   = 800000;
constexpr int FEAT = 256;
constexpr int HID  = 64;
constexpr int OUTD = 40;
constexpr int NC   = (NN + 255) / 256;     // 196 scan chunks
constexpr int FCH  = 2048;                  // fill: edges per chunk
constexpr int NCH  = (NE + FCH - 1) / FCH;  // 391 chunks

typedef short bf16x8 __attribute__((ext_vector_type(8)));
typedef float f32x4  __attribute__((ext_vector_type(4)));
typedef float f32x2  __attribute__((ext_vector_type(2)));

__device__ __forceinline__ float b2f(__hip_bfloat16 v) { return __bfloat162float(v); }
__device__ __forceinline__ float bflo(unsigned u) { return __uint_as_float(u << 16); }
__device__ __forceinline__ float bfhi(unsigned u) { return __uint_as_float(u & 0xffff0000u); }
__device__ __forceinline__ unsigned short f2bu(float f) {
    __hip_bfloat16 h = __float2bfloat16(f);
    return *(unsigned short*)&h;
}
__device__ __forceinline__ unsigned pack2bf(float a, float b) {
    return (unsigned)f2bu(a) | ((unsigned)f2bu(b) << 16);
}
__device__ __forceinline__ float loadF(const void* p, int i, bool f32) {
    return f32 ? ((const float*)p)[i] : b2f(((const __hip_bfloat16*)p)[i]);
}
__device__ __forceinline__ int loadE(const int* ei, int e, int row, bool i64) {
    long long idx = (long long)row * NE + e;
    return i64 ? ei[2 * idx] : ei[idx];
}
__device__ __forceinline__ bf16x8 pack8(float4 a, float4 b) {
    bf16x8 r;
    r[0] = (short)f2bu(a.x); r[1] = (short)f2bu(a.y);
    r[2] = (short)f2bu(a.z); r[3] = (short)f2bu(a.w);
    r[4] = (short)f2bu(b.x); r[5] = (short)f2bu(b.y);
    r[6] = (short)f2bu(b.z); r[7] = (short)f2bu(b.w);
    return r;
}

// ---- fp8 e4m3 (OCP) pack/unpack: HW cvt if available, exact SW fallback ----
#if __has_builtin(__builtin_amdgcn_cvt_pk_f32_fp8) && __has_builtin(__builtin_amdgcn_cvt_pk_fp8_f32)
__device__ __forceinline__ void unpack_fp8x4(unsigned u, float& f0, float& f1,
                                             float& f2, float& f3) {
    f32x2 lo = __builtin_amdgcn_cvt_pk_f32_fp8((int)u, false);
    f32x2 hi = __builtin_amdgcn_cvt_pk_f32_fp8((int)u, true);
    f0 = lo[0]; f1 = lo[1]; f2 = hi[0]; f3 = hi[1];
}
__device__ __forceinline__ unsigned pack_fp8x4(float a, float b, float c, float d) {
    int v = 0;
    v = __builtin_amdgcn_cvt_pk_fp8_f32(a, b, v, false);
    v = __builtin_amdgcn_cvt_pk_fp8_f32(c, d, v, true);
    return (unsigned)v;
}
#else
__device__ __forceinline__ float dec8(unsigned b) {
    return __uint_as_float(((b & 0x80u) << 24) | ((b & 0x7fu) << 20)) * 0x1p120f;
}
__device__ __forceinline__ void unpack_fp8x4(unsigned u, float& f0, float& f1,
                                             float& f2, float& f3) {
    f0 = dec8(u & 0xff); f1 = dec8((u >> 8) & 0xff);
    f2 = dec8((u >> 16) & 0xff); f3 = dec8(u >> 24);
}
__device__ __forceinline__ unsigned enc8(float f) {
    float a = fabsf(f) * 0x1p-120f;
    unsigned ub = __float_as_uint(a);
    unsigned lsb = (ub >> 20) & 1u;
    ub += 0x7FFFFu + lsb;                       // RNE into 3-bit mantissa
    unsigned v = (ub >> 20) & 0x7fu;
    if (v > 0x7e) v = 0x7e;                     // clamp (never expected)
    return v | ((__float_as_uint(f) >> 24) & 0x80u);
}
__device__ __forceinline__ unsigned pack_fp8x4(float a, float b, float c, float d) {
    return enc8(a) | (enc8(b) << 8) | (enc8(c) << 16) | (enc8(d) << 24);
}
#endif

// ---- zero + dtype detection + h2 pad-row zero ------------------------------
__global__ __launch_bounds__(256) void k_zero(const unsigned* __restrict__ xw,
                                              const int* __restrict__ ew,
                                              int* flags, int* cnt,
                                              unsigned* __restrict__ h2pad) {
    int i = blockIdx.x * 256 + threadIdx.x;
    if (i < NN) cnt[i] = 0;
    if (blockIdx.x == 0 && threadIdx.x < 16) h2pad[threadIdx.x] = 0;  // fp8 zero row
    if (blockIdx.x == 0 && threadIdx.x == 0) {
        int outliers = 0;
        for (int k = 0; k < 256; k++) {
            int e = (xw[k] >> 7) & 0xFF;   // exponent of low bf16 half
            if (e < 100 || e > 140) outliers++;
        }
        flags[0] = (outliers > 64) ? 1 : 0;
        int nz = 0;
        for (int k = 1; k < 64; k += 2)
            if (ew[k] != 0) nz++;
        flags[1] = (nz == 0) ? 1 : 0;
    }
}

// ---- CSR build -------------------------------------------------------------
__global__ __launch_bounds__(256) void k_hist(const int* __restrict__ ei,
                                              const int* __restrict__ flags,
                                              int* cnt, int* __restrict__ rank) {
    const bool i64 = flags[1] != 0;
    int e = blockIdx.x * 256 + threadIdx.x;
    if (e < NE) rank[e] = atomicAdd(&cnt[loadE(ei, e, 1, i64)], 1);
}
__global__ __launch_bounds__(256) void k_scan1(const int* __restrict__ cnt,
                                               int* row_start, int* partial, float* dinv) {
    __shared__ int s[256];
    int t = threadIdx.x, i = blockIdx.x * 256 + t;
    int v = (i < NN) ? cnt[i] : 0;
    if (i < NN) dinv[i] = rsqrtf(1.0f + (float)v);   // +1 self loop
    s[t] = v;
    __syncthreads();
    for (int off = 1; off < 256; off <<= 1) {
        int tmp = (t >= off) ? s[t - off] : 0;
        __syncthreads();
        s[t] += tmp;
        __syncthreads();
    }
    if (i < NN) row_start[i] = s[t] - v;       // exclusive within chunk
    if (t == 255) partial[blockIdx.x] = s[255];
}
// single block: pp[c] = exclusive prefix of partial[0..NC)
__global__ __launch_bounds__(256) void k_scan2p(const int* __restrict__ partial, int* pp) {
    __shared__ int s[256];
    int t = threadIdx.x;
    int v = (t < NC) ? partial[t] : 0;
    s[t] = v;
    __syncthreads();
    for (int off = 1; off < 256; off <<= 1) {
        int tmp = (t >= off) ? s[t - off] : 0;
        __syncthreads();
        s[t] += tmp;
        __syncthreads();
    }
    pp[t] = s[t] - v;
}
// Atomic-free fill; 8 blocks per chunk, class = dst/6250 for XCD write locality.
__global__ __launch_bounds__(256) void k_fill(const int* __restrict__ ei,
                                              const int* __restrict__ flags,
                                              const int* __restrict__ row_start,
                                              const int* __restrict__ pp,
                                              const int* __restrict__ rank,
                                              unsigned short* __restrict__ csr16) {
    const bool i64 = flags[1] != 0;
    const int cls = blockIdx.x & 7;
    const int e0 = (blockIdx.x >> 3) * FCH;
#pragma unroll
    for (int k = 0; k < FCH / 256; k++) {
        int e = e0 + k * 256 + threadIdx.x;
        if (e < NE) {
            int d = loadE(ei, e, 1, i64);
            if (d / 6250 == cls) {
                int s = loadE(ei, e, 0, i64);
                csr16[row_start[d] + pp[d >> 8] + rank[e]] = (unsigned short)s;
            }
        }
    }
}

// ---- layer 1 GEMM (MFMA): h1' = (x @ W1) * dinv[row]; zero rows >= NN ------
__global__ __launch_bounds__(256) void k_gemm1(const void* __restrict__ xb,
                                               const void* __restrict__ W1,
                                               const float* __restrict__ dinv,
                                               const int* __restrict__ flags,
                                               unsigned short* __restrict__ h1u) {
    __shared__ __align__(16) unsigned short wt16[64 * 264];
    const bool f32 = flags[0] != 0;
    const int t = threadIdx.x;
    if (f32) {
        const float* wf = (const float*)W1;
        for (int i = t * 4; i < FEAT * HID; i += 1024) {
            float4 w = *(const float4*)(wf + i);
            int k = i >> 6, n0 = i & 63;
            wt16[(n0 + 0) * 264 + k] = f2bu(w.x);
            wt16[(n0 + 1) * 264 + k] = f2bu(w.y);
            wt16[(n0 + 2) * 264 + k] = f2bu(w.z);
            wt16[(n0 + 3) * 264 + k] = f2bu(w.w);
        }
    } else {
        const unsigned short* wu = (const unsigned short*)W1;
        for (int i = t * 4; i < FEAT * HID; i += 1024) {
            ushort4 w = *(const ushort4*)(wu + i);
            int k = i >> 6, n0 = i & 63;
            wt16[(n0 + 0) * 264 + k] = w.x;
            wt16[(n0 + 1) * 264 + k] = w.y;
            wt16[(n0 + 2) * 264 + k] = w.z;
            wt16[(n0 + 3) * 264 + k] = w.w;
        }
    }
    const int wv = t >> 6, lane = t & 63, l15 = lane & 15, quad = lane >> 4;
    const int gr = blockIdx.x * 64 + wv * 16 + l15;
    const bool rowok = gr < NN;
    f32x4 acc[4];
#pragma unroll
    for (int nt = 0; nt < 4; nt++) acc[nt] = (f32x4){0.f, 0.f, 0.f, 0.f};
    __syncthreads();

    if (f32) {
        const float* xr = (const float*)xb + (size_t)gr * FEAT + quad * 8;
        float4 z4 = make_float4(0, 0, 0, 0);
        float4 c0 = rowok ? *(const float4*)xr : z4;
        float4 c1 = rowok ? *(const float4*)(xr + 4) : z4;
#pragma unroll
        for (int ks = 0; ks < 8; ks++) {
            float4 n0 = z4, n1 = z4;
            if (ks < 7 && rowok) {
                n0 = *(const float4*)(xr + (ks + 1) * 32);
                n1 = *(const float4*)(xr + (ks + 1) * 32 + 4);
            }
            bf16x8 a = pack8(c0, c1);
            const unsigned short* wk = wt16 + ks * 32 + quad * 8;
#pragma unroll
            for (int nt = 0; nt < 4; nt++) {
                bf16x8 b = *(const bf16x8*)(wk + (size_t)(nt * 16 + l15) * 264);
                acc[nt] = __builtin_amdgcn_mfma_f32_16x16x32_bf16(a, b, acc[nt], 0, 0, 0);
            }
            c0 = n0; c1 = n1;
        }
    } else {
        const unsigned short* xr = (const unsigned short*)xb + (size_t)gr * FEAT + quad * 8;
        bf16x8 zz = (bf16x8){0, 0, 0, 0, 0, 0, 0, 0};
        bf16x8 cur = rowok ? *(const bf16x8*)xr : zz;
#pragma unroll
        for (int ks = 0; ks < 8; ks++) {
            bf16x8 nxt = zz;
            if (ks < 7 && rowok) nxt = *(const bf16x8*)(xr + (ks + 1) * 32);
            const unsigned short* wk = wt16 + ks * 32 + quad * 8;
#pragma unroll
            for (int nt = 0; nt < 4; nt++) {
                bf16x8 b = *(const bf16x8*)(wk + (size_t)(nt * 16 + l15) * 264);
                acc[nt] = __builtin_amdgcn_mfma_f32_16x16x32_bf16(cur, b, acc[nt], 0, 0, 0);
            }
            cur = nxt;
        }
    }
    const int rbase = blockIdx.x * 64 + wv * 16 + quad * 4;
    float dv[4];
#pragma unroll
    for (int r = 0; r < 4; r++) dv[r] = (rbase + r < NN) ? dinv[rbase + r] : 0.f;
#pragma unroll
    for (int r = 0; r < 4; r++) {
        int grow = rbase + r;   // < NNP always (grid covers 50048 rows)
#pragma unroll
        for (int nt = 0; nt < 4; nt++)
            h1u[(size_t)grow * HID + nt * 16 + l15] = f2bu(acc[nt][r] * dv[r]);
    }
}

// ---- fused: s = sum h1'[{n}uN(n)] ; g = relu(dn*s + b1) ; h2' = dn*(g@W2) --
// Gather loop = best-known R2 form. h2 OUTPUT now fp8 e4m3, 16-dword rows.
__global__ __launch_bounds__(256, 4) void k_gather1f(const uint2* __restrict__ h1v,
                                                  const float* __restrict__ dinv,
                                                  const int* __restrict__ row_start,
                                                  const int* __restrict__ pp,
                                                  const int* __restrict__ cnt,
                                                  const unsigned short* __restrict__ csr16,
                                                  const void* __restrict__ W2,
                                                  const void* __restrict__ b1,
                                                  const int* __restrict__ flags,
                                                  unsigned* __restrict__ h2f) {
    __shared__ __align__(16) float w2t[OUTD * 68];   // [col][k], stride 68
    __shared__ __align__(16) float gbuf[16 * 68];    // [node][k], stride 68
    __shared__ __align__(16) float obuf[16][40];     // [node][col] f32 pre-pack
    __shared__ float dns[16];
    const bool f32 = flags[0] != 0;
    const int t = threadIdx.x;
    for (int i = t; i < HID * OUTD; i += 256) {
        int c = i >> 6, k = i & 63;
        w2t[c * 68 + k] = loadF(W2, (size_t)k * OUTD + c, f32);
    }
    const int nl = t >> 4, l16 = t & 15;
    const int n = blockIdx.x * 16 + nl;      // < NN (grid exact)
    const float dn = dinv[n];
    uint2 u0 = h1v[n * 16 + l16];            // fits int: < 800016
    float a0 = bflo(u0.x), a1 = bfhi(u0.x), a2 = bflo(u0.y), a3 = bfhi(u0.y);
    float e0 = 0.f, e1 = 0.f, e2 = 0.f, e3 = 0.f;
    const int rs = row_start[n] + pp[n >> 8], c = cnt[n];
    for (int base = 0; base < c; base += 16) {
        int rem = c - base;
        int sv = (l16 < rem) ? (int)csr16[rs + base + l16] : ZR;
        uint2 b[8], d[8];
#pragma unroll
        for (int j = 0; j < 8; j++) {
            int s = __shfl(sv, j, 16);
            b[j] = h1v[(s << 4) | l16];
        }
#pragma unroll
        for (int j = 0; j < 8; j++) {
            int s = __shfl(sv, j + 8, 16);
            d[j] = h1v[(s << 4) | l16];
        }
#pragma unroll
        for (int j = 0; j < 8; j++) {
            a0 += bflo(b[j].x); a1 += bfhi(b[j].x);
            a2 += bflo(b[j].y); a3 += bfhi(b[j].y);
            e0 += bflo(d[j].x); e1 += bfhi(d[j].x);
            e2 += bflo(d[j].y); e3 += bfhi(d[j].y);
        }
    }
    int cb = 4 * l16;
    float g0 = fmaxf(dn * (a0 + e0) + loadF(b1, cb, f32), 0.f);
    float g1 = fmaxf(dn * (a1 + e1) + loadF(b1, cb + 1, f32), 0.f);
    float g2 = fmaxf(dn * (a2 + e2) + loadF(b1, cb + 2, f32), 0.f);
    float g3 = fmaxf(dn * (a3 + e3) + loadF(b1, cb + 3, f32), 0.f);
    *(float4*)(gbuf + nl * 68 + cb) = make_float4(g0, g1, g2, g3);
    if (l16 == 0) dns[nl] = dn;
    __syncthreads();
    for (int idx = t; idx < 16 * OUTD; idx += 256) {
        int node = idx / OUTD, col = idx % OUTD;
        const float4* gp = (const float4*)(gbuf + node * 68);
        const float4* wp = (const float4*)(w2t + col * 68);
        float o = 0.f;
#pragma unroll 4
        for (int k4 = 0; k4 < 16; k4++) {
            float4 a = gp[k4], b = wp[k4];
            o += a.x * b.x + a.y * b.y + a.z * b.z + a.w * b.w;
        }
        obuf[node][col] = o * dns[node];
    }
    __syncthreads();
    if (t < 160) {
        int node = t / 10, dw = t % 10;
        const float* op = obuf[node] + dw * 4;
        h2f[(blockIdx.x * 16 + node) * 16 + dw] =
            pack_fp8x4(op[0], op[1], op[2], op[3]);
    }
}

// ---- prewarm: pull fp8 h2 (3.2MB) into every XCD's L2 ----------------------
// block b -> XCD b%8 (round-robin); slice b>>3 of 64; all 8 XCDs read all slices.
__global__ __launch_bounds__(256) void k_warm(const uint4* __restrict__ h2q, int* flags) {
    const int total4 = NNP * 4;                 // 200192 uint4
    const int per = (total4 + 63) / 64;         // 3129
    const int s = blockIdx.x >> 3;
    const int lo = s * per, hi = min(lo + per, total4);
    unsigned acc = 0;
    for (int i = lo + threadIdx.x; i < hi; i += 256) {
        uint4 v = h2q[i];
        acc += v.x ^ v.y ^ v.z ^ v.w;
    }
    if (acc == 0x9e3779b9u) flags[15] = (int)acc;   // keeps loads live; flags[15] unused
}

// ---- CSR gather layer 2 (fp8 h2, 1 line/row) + bias + log_softmax ----------
__global__ __launch_bounds__(256, 4) void k_gather2(const unsigned* __restrict__ h2f,
                                                 const float* __restrict__ dinv,
                                                 const int* __restrict__ row_start,
                                                 const int* __restrict__ pp,
                                                 const int* __restrict__ cnt,
                                                 const unsigned short* __restrict__ csr16,
                                                 const void* __restrict__ b2,
                                                 const int* __restrict__ flags,
                                                 void* __restrict__ out) {
    const bool f32 = flags[0] != 0;
    const int t = threadIdx.x;
    const int nl = t >> 4, l16 = t & 15;
    const int n = blockIdx.x * 16 + nl;      // < NN (grid exact)
    const bool act = l16 < 10;               // 10 dwords (40 fp8 cols) per row
    const float dn = dinv[n];
    const int lclamp = act ? l16 : 9;        // inactive lanes read lane-9 slot (discarded)
    float a0, a1, a2, a3;
    unpack_fp8x4(h2f[n * 16 + lclamp], a0, a1, a2, a3);   // self row
    float e0 = 0.f, e1 = 0.f, e2 = 0.f, e3 = 0.f;
    const int rs = row_start[n] + pp[n >> 8], c = cnt[n];
    for (int base = 0; base < c; base += 16) {
        int rem = c - base;
        int sv = (l16 < rem) ? (int)csr16[rs + base + l16] : ZR;
        unsigned b[8], d[8];
#pragma unroll
        for (int j = 0; j < 8; j++) {
            int s = __shfl(sv, j, 16);
            b[j] = h2f[(s << 4) + lclamp];
        }
#pragma unroll
        for (int j = 0; j < 8; j++) {
            int s = __shfl(sv, j + 8, 16);
            d[j] = h2f[(s << 4) + lclamp];
        }
#pragma unroll
        for (int j = 0; j < 8; j++) {
            float x0, x1, x2, x3, y0, y1, y2, y3;
            unpack_fp8x4(b[j], x0, x1, x2, x3);
            unpack_fp8x4(d[j], y0, y1, y2, y3);
            a0 += x0; a1 += x1; a2 += x2; a3 += x3;
            e0 += y0; e1 += y1; e2 += y2; e3 += y3;
        }
    }
    int cb = 4 * l16;
    float v0 = -3.0e38f, v1 = -3.0e38f, v2 = -3.0e38f, v3 = -3.0e38f;
    if (act) {
        v0 = dn * (a0 + e0) + loadF(b2, cb, f32);
        v1 = dn * (a1 + e1) + loadF(b2, cb + 1, f32);
        v2 = dn * (a2 + e2) + loadF(b2, cb + 2, f32);
        v3 = dn * (a3 + e3) + loadF(b2, cb + 3, f32);
    }
    float mx = fmaxf(fmaxf(v0, v1), fmaxf(v2, v3));
#pragma unroll
    for (int off = 8; off; off >>= 1) mx = fmaxf(mx, __shfl_xor(mx, off, 16));
    float ev = act ? expf(v0 - mx) + expf(v1 - mx) + expf(v2 - mx) + expf(v3 - mx) : 0.f;
#pragma unroll
    for (int off = 8; off; off >>= 1) ev += __shfl_xor(ev, off, 16);
    float lg = logf(ev);
    if (act) {
        float r0 = v0 - mx - lg, r1 = v1 - mx - lg;
        float r2 = v2 - mx - lg, r3 = v3 - mx - lg;
        if (f32) {
            *(float4*)((float*)out + (size_t)n * OUTD + cb) = make_float4(r0, r1, r2, r3);
        } else {
            ((uint2*)out)[(size_t)n * 10 + l16] = make_uint2(pack2bf(r0, r1), pack2bf(r2, r3));
        }
    }
}

extern "C" void kernel_launch(void* const* d_in, const int* in_sizes, int n_in,
                              void* d_out, int out_size, void* d_ws, size_t ws_size,
                              hipStream_t stream) {
    const void* x  = d_in[0];
    const int*  ei = (const int*)d_in[1];
    const void* W1 = d_in[2];
    const void* b1 = d_in[3];
    const void* W2 = d_in[4];
    const void* b2 = d_in[5];

    // ws layout (4-byte words):
    // flags[16] | dinv[50048] | cnt[50048] | row_start[50048] | partial[256] |
    // pp[256] | rank[800000] | csr16 ushort[800000] | h1' bf16 [NNP*64] |
    // h2' fp8 [NNP*16 dwords = 3.2MB]   (~15 MB)
    float* ws        = (float*)d_ws;
    int*   flags     = (int*)ws;
    float* dinv      = ws + 16;
    int*   cnt       = (int*)(dinv + 50048);
    int*   row_start = cnt + 50048;
    int*   partial   = row_start + 50048;
    int*   pp        = partial + 256;
    int*   rank      = pp + 256;
    unsigned short* csr16 = (unsigned short*)(rank + NE);
    unsigned short* h1u   = csr16 + NE;
    unsigned* h2f   = (unsigned*)(h1u + (size_t)NNP * HID);   // [NNP][16] dwords
    unsigned* h2pad = h2f + (size_t)ZR * 16;                  // 16 dwords

    k_zero  <<<(NN + 255) / 256, 256, 0, stream>>>((const unsigned*)x, ei, flags, cnt, h2pad);
    k_hist  <<<(NE + 255) / 256, 256, 0, stream>>>(ei, flags, cnt, rank);
    k_scan1 <<<NC, 256, 0, stream>>>(cnt, row_start, partial, dinv);
    k_scan2p<<<1, 256, 0, stream>>>(partial, pp);
    k_fill  <<<NCH * 8, 256, 0, stream>>>(ei, flags, row_start, pp, rank, csr16);
    k_gemm1 <<<NNP / 64, 256, 0, stream>>>(x, W1, dinv, flags, h1u);
    k_gather1f<<<NN / 16, 256, 0, stream>>>((const uint2*)h1u, dinv, row_start, pp, cnt, csr16,
                                            W2, b1, flags, h2f);
    k_warm  <<<512, 256, 0, stream>>>((const uint4*)h2f, flags);
    k_gather2<<<NN / 16, 256, 0, stream>>>(h2f, dinv, row_start, pp, cnt, csr16,
                                           b2, flags, d_out);
}

// Round 7
// 220.889 us; speedup vs baseline: 1.1151x; 1.0589x over previous
//
#include <hip/hip_runtime.h>
#include <hip/hip_bf16.h>

// GCN 2-layer: N=50000 nodes, E=800000 edges, 256 -> 64 (relu) -> 40 (log_softmax)
// Gather model (R0-R6): per-row-touch rate ~20k/us is invariant under schedule
// depth (R3/R5), line count (R6 fp8), and L2 prewarm (R6) => structural cost
// of divergent gather; parked at ~84us combined. R7 attacks the OTHER ~150us:
// (1) k_zero's dtype detection ran 288 serial loads on ONE thread -> now
//     wave-parallel (64 lanes + shfl reduce);
// (2) k_fill re-read dst+rank 8x (once per class) -> now one block per chunk,
//     dst/src/rank staged in LDS (24KB), 8-class loop reads LDS (traffic /8);
// (3) k_warm dropped (R6: prewarm ~null). fp8 h2 kept (>= bf16).

constexpr int NN   = 50000;
constexpr int NNP  = 50048;                 // padded row count (zero rows >= NN)
constexpr int ZR   = 50000;                 // zero-row index for padding lanes
constexpr int NE   = 800000;
constexpr int FEAT = 256;
constexpr int HID  = 64;
constexpr int OUTD = 40;
constexpr int NC   = (NN + 255) / 256;     // 196 scan chunks
constexpr int FCH  = 2048;                  // fill: edges per chunk
constexpr int NCH  = (NE + FCH - 1) / FCH;  // 391 chunks

typedef short bf16x8 __attribute__((ext_vector_type(8)));
typedef float f32x4  __attribute__((ext_vector_type(4)));
typedef float f32x2  __attribute__((ext_vector_type(2)));

__device__ __forceinline__ float b2f(__hip_bfloat16 v) { return __bfloat162float(v); }
__device__ __forceinline__ float bflo(unsigned u) { return __uint_as_float(u << 16); }
__device__ __forceinline__ float bfhi(unsigned u) { return __uint_as_float(u & 0xffff0000u); }
__device__ __forceinline__ unsigned short f2bu(float f) {
    __hip_bfloat16 h = __float2bfloat16(f);
    return *(unsigned short*)&h;
}
__device__ __forceinline__ unsigned pack2bf(float a, float b) {
    return (unsigned)f2bu(a) | ((unsigned)f2bu(b) << 16);
}
__device__ __forceinline__ float loadF(const void* p, int i, bool f32) {
    return f32 ? ((const float*)p)[i] : b2f(((const __hip_bfloat16*)p)[i]);
}
__device__ __forceinline__ int loadE(const int* ei, int e, int row, bool i64) {
    long long idx = (long long)row * NE + e;
    return i64 ? ei[2 * idx] : ei[idx];
}
__device__ __forceinline__ bf16x8 pack8(float4 a, float4 b) {
    bf16x8 r;
    r[0] = (short)f2bu(a.x); r[1] = (short)f2bu(a.y);
    r[2] = (short)f2bu(a.z); r[3] = (short)f2bu(a.w);
    r[4] = (short)f2bu(b.x); r[5] = (short)f2bu(b.y);
    r[6] = (short)f2bu(b.z); r[7] = (short)f2bu(b.w);
    return r;
}

// ---- fp8 e4m3 (OCP) pack/unpack: HW cvt if available, exact SW fallback ----
#if __has_builtin(__builtin_amdgcn_cvt_pk_f32_fp8) && __has_builtin(__builtin_amdgcn_cvt_pk_fp8_f32)
__device__ __forceinline__ void unpack_fp8x4(unsigned u, float& f0, float& f1,
                                             float& f2, float& f3) {
    f32x2 lo = __builtin_amdgcn_cvt_pk_f32_fp8((int)u, false);
    f32x2 hi = __builtin_amdgcn_cvt_pk_f32_fp8((int)u, true);
    f0 = lo[0]; f1 = lo[1]; f2 = hi[0]; f3 = hi[1];
}
__device__ __forceinline__ unsigned pack_fp8x4(float a, float b, float c, float d) {
    int v = 0;
    v = __builtin_amdgcn_cvt_pk_fp8_f32(a, b, v, false);
    v = __builtin_amdgcn_cvt_pk_fp8_f32(c, d, v, true);
    return (unsigned)v;
}
#else
__device__ __forceinline__ float dec8(unsigned b) {
    return __uint_as_float(((b & 0x80u) << 24) | ((b & 0x7fu) << 20)) * 0x1p120f;
}
__device__ __forceinline__ void unpack_fp8x4(unsigned u, float& f0, float& f1,
                                             float& f2, float& f3) {
    f0 = dec8(u & 0xff); f1 = dec8((u >> 8) & 0xff);
    f2 = dec8((u >> 16) & 0xff); f3 = dec8(u >> 24);
}
__device__ __forceinline__ unsigned enc8(float f) {
    float a = fabsf(f) * 0x1p-120f;
    unsigned ub = __float_as_uint(a);
    unsigned lsb = (ub >> 20) & 1u;
    ub += 0x7FFFFu + lsb;                       // RNE into 3-bit mantissa
    unsigned v = (ub >> 20) & 0x7fu;
    if (v > 0x7e) v = 0x7e;                     // clamp (never expected)
    return v | ((__float_as_uint(f) >> 24) & 0x80u);
}
__device__ __forceinline__ unsigned pack_fp8x4(float a, float b, float c, float d) {
    return enc8(a) | (enc8(b) << 8) | (enc8(c) << 16) | (enc8(d) << 24);
}
#endif

// ---- zero + dtype detection (wave-parallel) + h2 pad-row zero --------------
__global__ __launch_bounds__(256) void k_zero(const unsigned* __restrict__ xw,
                                              const int* __restrict__ ew,
                                              int* flags, int* cnt,
                                              unsigned* __restrict__ h2pad) {
    int i = blockIdx.x * 256 + threadIdx.x;
    if (i < NN) cnt[i] = 0;
    if (blockIdx.x == 0 && threadIdx.x < 16) h2pad[threadIdx.x] = 0;  // fp8 zero row
    if (blockIdx.x == 0 && threadIdx.x < 64) {   // wave 0: parallel detection
        const int lane = threadIdx.x;
        int outliers = 0;
#pragma unroll
        for (int k = lane; k < 256; k += 64) {
            int e = (xw[k] >> 7) & 0xFF;   // exponent of low bf16 half
            if (e < 100 || e > 140) outliers++;
        }
        int nz = 0;
        if (lane < 32) {                    // odd words 1,3,...,63 of edge data
            int k = 1 + 2 * lane;
            nz = (ew[k] != 0) ? 1 : 0;
        }
#pragma unroll
        for (int off = 32; off; off >>= 1) {
            outliers += __shfl_down(outliers, off, 64);
            nz       += __shfl_down(nz, off, 64);
        }
        if (lane == 0) {
            flags[0] = (outliers > 64) ? 1 : 0;
            flags[1] = (nz == 0) ? 1 : 0;
        }
    }
}

// ---- CSR build -------------------------------------------------------------
__global__ __launch_bounds__(256) void k_hist(const int* __restrict__ ei,
                                              const int* __restrict__ flags,
                                              int* cnt, int* __restrict__ rank) {
    const bool i64 = flags[1] != 0;
    int e = blockIdx.x * 256 + threadIdx.x;
    if (e < NE) rank[e] = atomicAdd(&cnt[loadE(ei, e, 1, i64)], 1);
}
__global__ __launch_bounds__(256) void k_scan1(const int* __restrict__ cnt,
                                               int* row_start, int* partial, float* dinv) {
    __shared__ int s[256];
    int t = threadIdx.x, i = blockIdx.x * 256 + t;
    int v = (i < NN) ? cnt[i] : 0;
    if (i < NN) dinv[i] = rsqrtf(1.0f + (float)v);   // +1 self loop
    s[t] = v;
    __syncthreads();
    for (int off = 1; off < 256; off <<= 1) {
        int tmp = (t >= off) ? s[t - off] : 0;
        __syncthreads();
        s[t] += tmp;
        __syncthreads();
    }
    if (i < NN) row_start[i] = s[t] - v;       // exclusive within chunk
    if (t == 255) partial[blockIdx.x] = s[255];
}
// single block: pp[c] = exclusive prefix of partial[0..NC)
__global__ __launch_bounds__(256) void k_scan2p(const int* __restrict__ partial, int* pp) {
    __shared__ int s[256];
    int t = threadIdx.x;
    int v = (t < NC) ? partial[t] : 0;
    s[t] = v;
    __syncthreads();
    for (int off = 1; off < 256; off <<= 1) {
        int tmp = (t >= off) ? s[t - off] : 0;
        __syncthreads();
        s[t] += tmp;
        __syncthreads();
    }
    pp[t] = s[t] - v;
}
// Atomic-free fill; ONE block per chunk, dst/src/rank staged in LDS once,
// 8-class write loop (dst/6250) reads LDS -> global edge traffic /8.
__global__ __launch_bounds__(256) void k_fill(const int* __restrict__ ei,
                                              const int* __restrict__ flags,
                                              const int* __restrict__ row_start,
                                              const int* __restrict__ pp,
                                              const int* __restrict__ rank,
                                              unsigned short* __restrict__ csr16) {
    __shared__ int dstL[FCH], srcL[FCH], rnkL[FCH];   // 24 KB
    const bool i64 = flags[1] != 0;
    const int e0 = blockIdx.x * FCH;
    const int t = threadIdx.x;
#pragma unroll
    for (int k = 0; k < FCH / 256; k++) {
        int idx = k * 256 + t, e = e0 + idx;
        if (e < NE) {
            dstL[idx] = loadE(ei, e, 1, i64);
            srcL[idx] = loadE(ei, e, 0, i64);
            rnkL[idx] = rank[e];
        } else {
            dstL[idx] = -1;
        }
    }
    __syncthreads();
    for (int cls = 0; cls < 8; cls++) {
#pragma unroll
        for (int k = 0; k < FCH / 256; k++) {
            int idx = k * 256 + t;
            int d = dstL[idx];
            if (d >= 0 && d / 6250 == cls)
                csr16[row_start[d] + pp[d >> 8] + rnkL[idx]] = (unsigned short)srcL[idx];
        }
    }
}

// ---- layer 1 GEMM (MFMA): h1' = (x @ W1) * dinv[row]; zero rows >= NN ------
__global__ __launch_bounds__(256) void k_gemm1(const void* __restrict__ xb,
                                               const void* __restrict__ W1,
                                               const float* __restrict__ dinv,
                                               const int* __restrict__ flags,
                                               unsigned short* __restrict__ h1u) {
    __shared__ __align__(16) unsigned short wt16[64 * 264];
    const bool f32 = flags[0] != 0;
    const int t = threadIdx.x;
    if (f32) {
        const float* wf = (const float*)W1;
        for (int i = t * 4; i < FEAT * HID; i += 1024) {
            float4 w = *(const float4*)(wf + i);
            int k = i >> 6, n0 = i & 63;
            wt16[(n0 + 0) * 264 + k] = f2bu(w.x);
            wt16[(n0 + 1) * 264 + k] = f2bu(w.y);
            wt16[(n0 + 2) * 264 + k] = f2bu(w.z);
            wt16[(n0 + 3) * 264 + k] = f2bu(w.w);
        }
    } else {
        const unsigned short* wu = (const unsigned short*)W1;
        for (int i = t * 4; i < FEAT * HID; i += 1024) {
            ushort4 w = *(const ushort4*)(wu + i);
            int k = i >> 6, n0 = i & 63;
            wt16[(n0 + 0) * 264 + k] = w.x;
            wt16[(n0 + 1) * 264 + k] = w.y;
            wt16[(n0 + 2) * 264 + k] = w.z;
            wt16[(n0 + 3) * 264 + k] = w.w;
        }
    }
    const int wv = t >> 6, lane = t & 63, l15 = lane & 15, quad = lane >> 4;
    const int gr = blockIdx.x * 64 + wv * 16 + l15;
    const bool rowok = gr < NN;
    f32x4 acc[4];
#pragma unroll
    for (int nt = 0; nt < 4; nt++) acc[nt] = (f32x4){0.f, 0.f, 0.f, 0.f};
    __syncthreads();

    if (f32) {
        const float* xr = (const float*)xb + (size_t)gr * FEAT + quad * 8;
        float4 z4 = make_float4(0, 0, 0, 0);
        float4 c0 = rowok ? *(const float4*)xr : z4;
        float4 c1 = rowok ? *(const float4*)(xr + 4) : z4;
#pragma unroll
        for (int ks = 0; ks < 8; ks++) {
            float4 n0 = z4, n1 = z4;
            if (ks < 7 && rowok) {
                n0 = *(const float4*)(xr + (ks + 1) * 32);
                n1 = *(const float4*)(xr + (ks + 1) * 32 + 4);
            }
            bf16x8 a = pack8(c0, c1);
            const unsigned short* wk = wt16 + ks * 32 + quad * 8;
#pragma unroll
            for (int nt = 0; nt < 4; nt++) {
                bf16x8 b = *(const bf16x8*)(wk + (size_t)(nt * 16 + l15) * 264);
                acc[nt] = __builtin_amdgcn_mfma_f32_16x16x32_bf16(a, b, acc[nt], 0, 0, 0);
            }
            c0 = n0; c1 = n1;
        }
    } else {
        const unsigned short* xr = (const unsigned short*)xb + (size_t)gr * FEAT + quad * 8;
        bf16x8 zz = (bf16x8){0, 0, 0, 0, 0, 0, 0, 0};
        bf16x8 cur = rowok ? *(const bf16x8*)xr : zz;
#pragma unroll
        for (int ks = 0; ks < 8; ks++) {
            bf16x8 nxt = zz;
            if (ks < 7 && rowok) nxt = *(const bf16x8*)(xr + (ks + 1) * 32);
            const unsigned short* wk = wt16 + ks * 32 + quad * 8;
#pragma unroll
            for (int nt = 0; nt < 4; nt++) {
                bf16x8 b = *(const bf16x8*)(wk + (size_t)(nt * 16 + l15) * 264);
                acc[nt] = __builtin_amdgcn_mfma_f32_16x16x32_bf16(cur, b, acc[nt], 0, 0, 0);
            }
            cur = nxt;
        }
    }
    const int rbase = blockIdx.x * 64 + wv * 16 + quad * 4;
    float dv[4];
#pragma unroll
    for (int r = 0; r < 4; r++) dv[r] = (rbase + r < NN) ? dinv[rbase + r] : 0.f;
#pragma unroll
    for (int r = 0; r < 4; r++) {
        int grow = rbase + r;   // < NNP always (grid covers 50048 rows)
#pragma unroll
        for (int nt = 0; nt < 4; nt++)
            h1u[(size_t)grow * HID + nt * 16 + l15] = f2bu(acc[nt][r] * dv[r]);
    }
}

// ---- fused: s = sum h1'[{n}uN(n)] ; g = relu(dn*s + b1) ; h2' = dn*(g@W2) --
// Gather loop = best-known R2 form. h2 OUTPUT fp8 e4m3, 16-dword rows.
__global__ __launch_bounds__(256, 4) void k_gather1f(const uint2* __restrict__ h1v,
                                                  const float* __restrict__ dinv,
                                                  const int* __restrict__ row_start,
                                                  const int* __restrict__ pp,
                                                  const int* __restrict__ cnt,
                                                  const unsigned short* __restrict__ csr16,
                                                  const void* __restrict__ W2,
                                                  const void* __restrict__ b1,
                                                  const int* __restrict__ flags,
                                                  unsigned* __restrict__ h2f) {
    __shared__ __align__(16) float w2t[OUTD * 68];   // [col][k], stride 68
    __shared__ __align__(16) float gbuf[16 * 68];    // [node][k], stride 68
    __shared__ __align__(16) float obuf[16][40];     // [node][col] f32 pre-pack
    __shared__ float dns[16];
    const bool f32 = flags[0] != 0;
    const int t = threadIdx.x;
    for (int i = t; i < HID * OUTD; i += 256) {
        int c = i >> 6, k = i & 63;
        w2t[c * 68 + k] = loadF(W2, (size_t)k * OUTD + c, f32);
    }
    const int nl = t >> 4, l16 = t & 15;
    const int n = blockIdx.x * 16 + nl;      // < NN (grid exact)
    const float dn = dinv[n];
    uint2 u0 = h1v[n * 16 + l16];            // fits int: < 800016
    float a0 = bflo(u0.x), a1 = bfhi(u0.x), a2 = bflo(u0.y), a3 = bfhi(u0.y);
    float e0 = 0.f, e1 = 0.f, e2 = 0.f, e3 = 0.f;
    const int rs = row_start[n] + pp[n >> 8], c = cnt[n];
    for (int base = 0; base < c; base += 16) {
        int rem = c - base;
        int sv = (l16 < rem) ? (int)csr16[rs + base + l16] : ZR;
        uint2 b[8], d[8];
#pragma unroll
        for (int j = 0; j < 8; j++) {
            int s = __shfl(sv, j, 16);
            b[j] = h1v[(s << 4) | l16];
        }
#pragma unroll
        for (int j = 0; j < 8; j++) {
            int s = __shfl(sv, j + 8, 16);
            d[j] = h1v[(s << 4) | l16];
        }
#pragma unroll
        for (int j = 0; j < 8; j++) {
            a0 += bflo(b[j].x); a1 += bfhi(b[j].x);
            a2 += bflo(b[j].y); a3 += bfhi(b[j].y);
            e0 += bflo(d[j].x); e1 += bfhi(d[j].x);
            e2 += bflo(d[j].y); e3 += bfhi(d[j].y);
        }
    }
    int cb = 4 * l16;
    float g0 = fmaxf(dn * (a0 + e0) + loadF(b1, cb, f32), 0.f);
    float g1 = fmaxf(dn * (a1 + e1) + loadF(b1, cb + 1, f32), 0.f);
    float g2 = fmaxf(dn * (a2 + e2) + loadF(b1, cb + 2, f32), 0.f);
    float g3 = fmaxf(dn * (a3 + e3) + loadF(b1, cb + 3, f32), 0.f);
    *(float4*)(gbuf + nl * 68 + cb) = make_float4(g0, g1, g2, g3);
    if (l16 == 0) dns[nl] = dn;
    __syncthreads();
    for (int idx = t; idx < 16 * OUTD; idx += 256) {
        int node = idx / OUTD, col = idx % OUTD;
        const float4* gp = (const float4*)(gbuf + node * 68);
        const float4* wp = (const float4*)(w2t + col * 68);
        float o = 0.f;
#pragma unroll 4
        for (int k4 = 0; k4 < 16; k4++) {
            float4 a = gp[k4], b = wp[k4];
            o += a.x * b.x + a.y * b.y + a.z * b.z + a.w * b.w;
        }
        obuf[node][col] = o * dns[node];
    }
    __syncthreads();
    if (t < 160) {
        int node = t / 10, dw = t % 10;
        const float* op = obuf[node] + dw * 4;
        h2f[(blockIdx.x * 16 + node) * 16 + dw] =
            pack_fp8x4(op[0], op[1], op[2], op[3]);
    }
}

// ---- CSR gather layer 2 (fp8 h2, 1 line/row) + bias + log_softmax ----------
__global__ __launch_bounds__(256, 4) void k_gather2(const unsigned* __restrict__ h2f,
                                                 const float* __restrict__ dinv,
                                                 const int* __restrict__ row_start,
                                                 const int* __restrict__ pp,
                                                 const int* __restrict__ cnt,
                                                 const unsigned short* __restrict__ csr16,
                                                 const void* __restrict__ b2,
                                                 const int* __restrict__ flags,
                                                 void* __restrict__ out) {
    const bool f32 = flags[0] != 0;
    const int t = threadIdx.x;
    const int nl = t >> 4, l16 = t & 15;
    const int n = blockIdx.x * 16 + nl;      // < NN (grid exact)
    const bool act = l16 < 10;               // 10 dwords (40 fp8 cols) per row
    const float dn = dinv[n];
    const int lclamp = act ? l16 : 9;        // inactive lanes read lane-9 slot (discarded)
    float a0, a1, a2, a3;
    unpack_fp8x4(h2f[n * 16 + lclamp], a0, a1, a2, a3);   // self row
    float e0 = 0.f, e1 = 0.f, e2 = 0.f, e3 = 0.f;
    const int rs = row_start[n] + pp[n >> 8], c = cnt[n];
    for (int base = 0; base < c; base += 16) {
        int rem = c - base;
        int sv = (l16 < rem) ? (int)csr16[rs + base + l16] : ZR;
        unsigned b[8], d[8];
#pragma unroll
        for (int j = 0; j < 8; j++) {
            int s = __shfl(sv, j, 16);
            b[j] = h2f[(s << 4) + lclamp];
        }
#pragma unroll
        for (int j = 0; j < 8; j++) {
            int s = __shfl(sv, j + 8, 16);
            d[j] = h2f[(s << 4) + lclamp];
        }
#pragma unroll
        for (int j = 0; j < 8; j++) {
            float x0, x1, x2, x3, y0, y1, y2, y3;
            unpack_fp8x4(b[j], x0, x1, x2, x3);
            unpack_fp8x4(d[j], y0, y1, y2, y3);
            a0 += x0; a1 += x1; a2 += x2; a3 += x3;
            e0 += y0; e1 += y1; e2 += y2; e3 += y3;
        }
    }
    int cb = 4 * l16;
    float v0 = -3.0e38f, v1 = -3.0e38f, v2 = -3.0e38f, v3 = -3.0e38f;
    if (act) {
        v0 = dn * (a0 + e0) + loadF(b2, cb, f32);
        v1 = dn * (a1 + e1) + loadF(b2, cb + 1, f32);
        v2 = dn * (a2 + e2) + loadF(b2, cb + 2, f32);
        v3 = dn * (a3 + e3) + loadF(b2, cb + 3, f32);
    }
    float mx = fmaxf(fmaxf(v0, v1), fmaxf(v2, v3));
#pragma unroll
    for (int off = 8; off; off >>= 1) mx = fmaxf(mx, __shfl_xor(mx, off, 16));
    float ev = act ? expf(v0 - mx) + expf(v1 - mx) + expf(v2 - mx) + expf(v3 - mx) : 0.f;
#pragma unroll
    for (int off = 8; off; off >>= 1) ev += __shfl_xor(ev, off, 16);
    float lg = logf(ev);
    if (act) {
        float r0 = v0 - mx - lg, r1 = v1 - mx - lg;
        float r2 = v2 - mx - lg, r3 = v3 - mx - lg;
        if (f32) {
            *(float4*)((float*)out + (size_t)n * OUTD + cb) = make_float4(r0, r1, r2, r3);
        } else {
            ((uint2*)out)[(size_t)n * 10 + l16] = make_uint2(pack2bf(r0, r1), pack2bf(r2, r3));
        }
    }
}

extern "C" void kernel_launch(void* const* d_in, const int* in_sizes, int n_in,
                              void* d_out, int out_size, void* d_ws, size_t ws_size,
                              hipStream_t stream) {
    const void* x  = d_in[0];
    const int*  ei = (const int*)d_in[1];
    const void* W1 = d_in[2];
    const void* b1 = d_in[3];
    const void* W2 = d_in[4];
    const void* b2 = d_in[5];

    // ws layout (4-byte words):
    // flags[16] | dinv[50048] | cnt[50048] | row_start[50048] | partial[256] |
    // pp[256] | rank[800000] | csr16 ushort[800000] | h1' bf16 [NNP*64] |
    // h2' fp8 [NNP*16 dwords = 3.2MB]   (~15 MB)
    float* ws        = (float*)d_ws;
    int*   flags     = (int*)ws;
    float* dinv      = ws + 16;
    int*   cnt       = (int*)(dinv + 50048);
    int*   row_start = cnt + 50048;
    int*   partial   = row_start + 50048;
    int*   pp        = partial + 256;
    int*   rank      = pp + 256;
    unsigned short* csr16 = (unsigned short*)(rank + NE);
    unsigned short* h1u   = csr16 + NE;
    unsigned* h2f   = (unsigned*)(h1u + (size_t)NNP * HID);   // [NNP][16] dwords
    unsigned* h2pad = h2f + (size_t)ZR * 16;                  // 16 dwords

    k_zero  <<<(NN + 255) / 256, 256, 0, stream>>>((const unsigned*)x, ei, flags, cnt, h2pad);
    k_hist  <<<(NE + 255) / 256, 256, 0, stream>>>(ei, flags, cnt, rank);
    k_scan1 <<<NC, 256, 0, stream>>>(cnt, row_start, partial, dinv);
    k_scan2p<<<1, 256, 0, stream>>>(partial, pp);
    k_fill  <<<NCH, 256, 0, stream>>>(ei, flags, row_start, pp, rank, csr16);
    k_gemm1 <<<NNP / 64, 256, 0, stream>>>(x, W1, dinv, flags, h1u);
    k_gather1f<<<NN / 16, 256, 0, stream>>>((const uint2*)h1u, dinv, row_start, pp, cnt, csr16,
                                            W2, b1, flags, h2f);
    k_gather2<<<NN / 16, 256, 0, stream>>>(h2f, dinv, row_start, pp, cnt, csr16,
                                           b2, flags, d_out);
}

// Round 8
// 208.500 us; speedup vs baseline: 1.1813x; 1.0594x over previous
//
#include <hip/hip_runtime.h>
#include <hip/hip_bf16.h>

// GCN 2-layer: N=50000 nodes, E=800000 edges, 256 -> 64 (relu) -> 40 (log_softmax)
// Gather model (R0-R6): per-row-touch rate ~20k/us invariant under depth/lines/
// prewarm => parked (~78us combined). R7 (-13us): wave-parallel detect, LDS fill,
// warm dropped. Ledger: ~143us unexplained in build chain + 7 launch gaps.
// R8: consolidate 8 -> 6 kernels. k_build fuses {scan2p-in-LDS + fill} (blocks
// 0..NCH-1) with {gemm1} (blocks NCH..NCH+781) -> fill's scatter latency hides
// under gemm's streaming; 2 launch gaps removed. rank stored as uint8 (max
// degree ~40 << 255) -> rank traffic 3.2MB -> 0.8MB in hist+fill.

constexpr int NN   = 50000;
constexpr int NNP  = 50048;                 // padded row count (zero rows >= NN)
constexpr int ZR   = 50000;                 // zero-row index for padding lanes
constexpr int NE   = 800000;
constexpr int FEAT = 256;
constexpr int HID  = 64;
constexpr int OUTD = 40;
constexpr int NC   = (NN + 255) / 256;     // 196 scan chunks
constexpr int FCH  = 2048;                  // fill: edges per chunk
constexpr int NCH  = (NE + FCH - 1) / FCH;  // 391 chunks
constexpr int GB   = NNP / 64;              // 782 gemm blocks

typedef short bf16x8 __attribute__((ext_vector_type(8)));
typedef float f32x4  __attribute__((ext_vector_type(4)));
typedef float f32x2  __attribute__((ext_vector_type(2)));

__device__ __forceinline__ float b2f(__hip_bfloat16 v) { return __bfloat162float(v); }
__device__ __forceinline__ float bflo(unsigned u) { return __uint_as_float(u << 16); }
__device__ __forceinline__ float bfhi(unsigned u) { return __uint_as_float(u & 0xffff0000u); }
__device__ __forceinline__ unsigned short f2bu(float f) {
    __hip_bfloat16 h = __float2bfloat16(f);
    return *(unsigned short*)&h;
}
__device__ __forceinline__ unsigned pack2bf(float a, float b) {
    return (unsigned)f2bu(a) | ((unsigned)f2bu(b) << 16);
}
__device__ __forceinline__ float loadF(const void* p, int i, bool f32) {
    return f32 ? ((const float*)p)[i] : b2f(((const __hip_bfloat16*)p)[i]);
}
__device__ __forceinline__ int loadE(const int* ei, int e, int row, bool i64) {
    long long idx = (long long)row * NE + e;
    return i64 ? ei[2 * idx] : ei[idx];
}
__device__ __forceinline__ bf16x8 pack8(float4 a, float4 b) {
    bf16x8 r;
    r[0] = (short)f2bu(a.x); r[1] = (short)f2bu(a.y);
    r[2] = (short)f2bu(a.z); r[3] = (short)f2bu(a.w);
    r[4] = (short)f2bu(b.x); r[5] = (short)f2bu(b.y);
    r[6] = (short)f2bu(b.z); r[7] = (short)f2bu(b.w);
    return r;
}

// ---- fp8 e4m3 (OCP) pack/unpack: HW cvt if available, exact SW fallback ----
#if __has_builtin(__builtin_amdgcn_cvt_pk_f32_fp8) && __has_builtin(__builtin_amdgcn_cvt_pk_fp8_f32)
__device__ __forceinline__ void unpack_fp8x4(unsigned u, float& f0, float& f1,
                                             float& f2, float& f3) {
    f32x2 lo = __builtin_amdgcn_cvt_pk_f32_fp8((int)u, false);
    f32x2 hi = __builtin_amdgcn_cvt_pk_f32_fp8((int)u, true);
    f0 = lo[0]; f1 = lo[1]; f2 = hi[0]; f3 = hi[1];
}
__device__ __forceinline__ unsigned pack_fp8x4(float a, float b, float c, float d) {
    int v = 0;
    v = __builtin_amdgcn_cvt_pk_fp8_f32(a, b, v, false);
    v = __builtin_amdgcn_cvt_pk_fp8_f32(c, d, v, true);
    return (unsigned)v;
}
#else
__device__ __forceinline__ float dec8(unsigned b) {
    return __uint_as_float(((b & 0x80u) << 24) | ((b & 0x7fu) << 20)) * 0x1p120f;
}
__device__ __forceinline__ void unpack_fp8x4(unsigned u, float& f0, float& f1,
                                             float& f2, float& f3) {
    f0 = dec8(u & 0xff); f1 = dec8((u >> 8) & 0xff);
    f2 = dec8((u >> 16) & 0xff); f3 = dec8(u >> 24);
}
__device__ __forceinline__ unsigned enc8(float f) {
    float a = fabsf(f) * 0x1p-120f;
    unsigned ub = __float_as_uint(a);
    unsigned lsb = (ub >> 20) & 1u;
    ub += 0x7FFFFu + lsb;                       // RNE into 3-bit mantissa
    unsigned v = (ub >> 20) & 0x7fu;
    if (v > 0x7e) v = 0x7e;                     // clamp (never expected)
    return v | ((__float_as_uint(f) >> 24) & 0x80u);
}
__device__ __forceinline__ unsigned pack_fp8x4(float a, float b, float c, float d) {
    return enc8(a) | (enc8(b) << 8) | (enc8(c) << 16) | (enc8(d) << 24);
}
#endif

// ---- zero + dtype detection (wave-parallel) + h2 pad-row zero --------------
__global__ __launch_bounds__(256) void k_zero(const unsigned* __restrict__ xw,
                                              const int* __restrict__ ew,
                                              int* flags, int* cnt,
                                              unsigned* __restrict__ h2pad) {
    int i = blockIdx.x * 256 + threadIdx.x;
    if (i < NN) cnt[i] = 0;
    if (blockIdx.x == 0 && threadIdx.x < 16) h2pad[threadIdx.x] = 0;  // fp8 zero row
    if (blockIdx.x == 0 && threadIdx.x < 64) {   // wave 0: parallel detection
        const int lane = threadIdx.x;
        int outliers = 0;
#pragma unroll
        for (int k = lane; k < 256; k += 64) {
            int e = (xw[k] >> 7) & 0xFF;   // exponent of low bf16 half
            if (e < 100 || e > 140) outliers++;
        }
        int nz = 0;
        if (lane < 32) {                    // odd words 1,3,...,63 of edge data
            int k = 1 + 2 * lane;
            nz = (ew[k] != 0) ? 1 : 0;
        }
#pragma unroll
        for (int off = 32; off; off >>= 1) {
            outliers += __shfl_down(outliers, off, 64);
            nz       += __shfl_down(nz, off, 64);
        }
        if (lane == 0) {
            flags[0] = (outliers > 64) ? 1 : 0;
            flags[1] = (nz == 0) ? 1 : 0;
        }
    }
}

// ---- CSR build: hist (rank as uint8) ---------------------------------------
__global__ __launch_bounds__(256) void k_hist(const int* __restrict__ ei,
                                              const int* __restrict__ flags,
                                              int* cnt, unsigned char* __restrict__ rank8) {
    const bool i64 = flags[1] != 0;
    int e = blockIdx.x * 256 + threadIdx.x;
    if (e < NE) rank8[e] = (unsigned char)atomicAdd(&cnt[loadE(ei, e, 1, i64)], 1);
}
__global__ __launch_bounds__(256) void k_scan1(const int* __restrict__ cnt,
                                               int* row_start, int* partial, float* dinv) {
    __shared__ int s[256];
    int t = threadIdx.x, i = blockIdx.x * 256 + t;
    int v = (i < NN) ? cnt[i] : 0;
    if (i < NN) dinv[i] = rsqrtf(1.0f + (float)v);   // +1 self loop
    s[t] = v;
    __syncthreads();
    for (int off = 1; off < 256; off <<= 1) {
        int tmp = (t >= off) ? s[t - off] : 0;
        __syncthreads();
        s[t] += tmp;
        __syncthreads();
    }
    if (i < NN) row_start[i] = s[t] - v;       // exclusive within chunk
    if (t == 255) partial[blockIdx.x] = s[255];
}

// ---- fused build: blocks [0,NCH) = scan2p-in-LDS + LDS-staged fill;
//      blocks [NCH, NCH+GB) = gemm1 (h1' = (x@W1)*dinv). Independent work
//      runs concurrently; fill's scatter latency hides under gemm streaming.
__global__ __launch_bounds__(256) void k_build(const int* __restrict__ ei,
                                               const int* __restrict__ flags,
                                               const int* __restrict__ row_start,
                                               const int* __restrict__ partial,
                                               int* __restrict__ pp,
                                               const unsigned char* __restrict__ rank8,
                                               unsigned short* __restrict__ csr16,
                                               const void* __restrict__ xb,
                                               const void* __restrict__ W1,
                                               const float* __restrict__ dinv,
                                               unsigned short* __restrict__ h1u) {
    __shared__ __align__(16) unsigned char smem[64 * 264 * 2];   // 33792 B union
    const bool f32 = flags[0] != 0;
    const int t = threadIdx.x;

    if (blockIdx.x < NCH) {
        // ---------------- fill role ----------------
        const bool i64 = flags[1] != 0;
        int* dstL = (int*)smem;                       // [FCH] 8KB
        int* srcL = dstL + FCH;                       // [FCH] 8KB
        unsigned char* rnkL = (unsigned char*)(srcL + FCH);   // [FCH] 2KB
        int* ppL = (int*)(rnkL + FCH);                // [256] 1KB
        // exclusive scan of partial[0..NC) (every fill block re-derives)
        int v = (t < NC) ? partial[t] : 0;
        ppL[t] = v;
        __syncthreads();
        for (int off = 1; off < 256; off <<= 1) {
            int tmp = (t >= off) ? ppL[t - off] : 0;
            __syncthreads();
            ppL[t] += tmp;
            __syncthreads();
        }
        int excl = ppL[t] - v;
        __syncthreads();
        ppL[t] = excl;
        if (blockIdx.x == 0) pp[t] = excl;            // publish for gathers
        const int e0 = blockIdx.x * FCH;
#pragma unroll
        for (int k = 0; k < FCH / 256; k++) {
            int idx = k * 256 + t, e = e0 + idx;
            if (e < NE) {
                dstL[idx] = loadE(ei, e, 1, i64);
                srcL[idx] = loadE(ei, e, 0, i64);
                rnkL[idx] = rank8[e];
            } else {
                dstL[idx] = -1;
            }
        }
        __syncthreads();
        for (int cls = 0; cls < 8; cls++) {
#pragma unroll
            for (int k = 0; k < FCH / 256; k++) {
                int idx = k * 256 + t;
                int d = dstL[idx];
                if (d >= 0 && d / 6250 == cls)
                    csr16[row_start[d] + ppL[d >> 8] + (int)rnkL[idx]] =
                        (unsigned short)srcL[idx];
            }
        }
        return;
    }

    // ---------------- gemm role ----------------
    const int bid = blockIdx.x - NCH;                 // 0..GB-1
    unsigned short* wt16 = (unsigned short*)smem;     // [64*264]
    if (f32) {
        const float* wf = (const float*)W1;
        for (int i = t * 4; i < FEAT * HID; i += 1024) {
            float4 w = *(const float4*)(wf + i);
            int k = i >> 6, n0 = i & 63;
            wt16[(n0 + 0) * 264 + k] = f2bu(w.x);
            wt16[(n0 + 1) * 264 + k] = f2bu(w.y);
            wt16[(n0 + 2) * 264 + k] = f2bu(w.z);
            wt16[(n0 + 3) * 264 + k] = f2bu(w.w);
        }
    } else {
        const unsigned short* wu = (const unsigned short*)W1;
        for (int i = t * 4; i < FEAT * HID; i += 1024) {
            ushort4 w = *(const ushort4*)(wu + i);
            int k = i >> 6, n0 = i & 63;
            wt16[(n0 + 0) * 264 + k] = w.x;
            wt16[(n0 + 1) * 264 + k] = w.y;
            wt16[(n0 + 2) * 264 + k] = w.z;
            wt16[(n0 + 3) * 264 + k] = w.w;
        }
    }
    const int wv = t >> 6, lane = t & 63, l15 = lane & 15, quad = lane >> 4;
    const int gr = bid * 64 + wv * 16 + l15;
    const bool rowok = gr < NN;
    f32x4 acc[4];
#pragma unroll
    for (int nt = 0; nt < 4; nt++) acc[nt] = (f32x4){0.f, 0.f, 0.f, 0.f};
    __syncthreads();

    if (f32) {
        const float* xr = (const float*)xb + (size_t)gr * FEAT + quad * 8;
        float4 z4 = make_float4(0, 0, 0, 0);
        float4 c0 = rowok ? *(const float4*)xr : z4;
        float4 c1 = rowok ? *(const float4*)(xr + 4) : z4;
#pragma unroll
        for (int ks = 0; ks < 8; ks++) {
            float4 n0 = z4, n1 = z4;
            if (ks < 7 && rowok) {
                n0 = *(const float4*)(xr + (ks + 1) * 32);
                n1 = *(const float4*)(xr + (ks + 1) * 32 + 4);
            }
            bf16x8 a = pack8(c0, c1);
            const unsigned short* wk = wt16 + ks * 32 + quad * 8;
#pragma unroll
            for (int nt = 0; nt < 4; nt++) {
                bf16x8 b = *(const bf16x8*)(wk + (size_t)(nt * 16 + l15) * 264);
                acc[nt] = __builtin_amdgcn_mfma_f32_16x16x32_bf16(a, b, acc[nt], 0, 0, 0);
            }
            c0 = n0; c1 = n1;
        }
    } else {
        const unsigned short* xr = (const unsigned short*)xb + (size_t)gr * FEAT + quad * 8;
        bf16x8 zz = (bf16x8){0, 0, 0, 0, 0, 0, 0, 0};
        bf16x8 cur = rowok ? *(const bf16x8*)xr : zz;
#pragma unroll
        for (int ks = 0; ks < 8; ks++) {
            bf16x8 nxt = zz;
            if (ks < 7 && rowok) nxt = *(const bf16x8*)(xr + (ks + 1) * 32);
            const unsigned short* wk = wt16 + ks * 32 + quad * 8;
#pragma unroll
            for (int nt = 0; nt < 4; nt++) {
                bf16x8 b = *(const bf16x8*)(wk + (size_t)(nt * 16 + l15) * 264);
                acc[nt] = __builtin_amdgcn_mfma_f32_16x16x32_bf16(cur, b, acc[nt], 0, 0, 0);
            }
            cur = nxt;
        }
    }
    const int rbase = bid * 64 + wv * 16 + quad * 4;
    float dv[4];
#pragma unroll
    for (int r = 0; r < 4; r++) dv[r] = (rbase + r < NN) ? dinv[rbase + r] : 0.f;
#pragma unroll
    for (int r = 0; r < 4; r++) {
        int grow = rbase + r;   // < NNP always
#pragma unroll
        for (int nt = 0; nt < 4; nt++)
            h1u[(size_t)grow * HID + nt * 16 + l15] = f2bu(acc[nt][r] * dv[r]);
    }
}

// ---- fused: s = sum h1'[{n}uN(n)] ; g = relu(dn*s + b1) ; h2' = dn*(g@W2) --
// Gather loop = best-known R2 form. h2 OUTPUT fp8 e4m3, 16-dword rows.
__global__ __launch_bounds__(256, 4) void k_gather1f(const uint2* __restrict__ h1v,
                                                  const float* __restrict__ dinv,
                                                  const int* __restrict__ row_start,
                                                  const int* __restrict__ pp,
                                                  const int* __restrict__ cnt,
                                                  const unsigned char* __restrict__ rank8_unused,
                                                  const unsigned short* __restrict__ csr16,
                                                  const void* __restrict__ W2,
                                                  const void* __restrict__ b1,
                                                  const int* __restrict__ flags,
                                                  unsigned* __restrict__ h2f) {
    __shared__ __align__(16) float w2t[OUTD * 68];   // [col][k], stride 68
    __shared__ __align__(16) float gbuf[16 * 68];    // [node][k], stride 68
    __shared__ __align__(16) float obuf[16][40];     // [node][col] f32 pre-pack
    __shared__ float dns[16];
    const bool f32 = flags[0] != 0;
    const int t = threadIdx.x;
    for (int i = t; i < HID * OUTD; i += 256) {
        int c = i >> 6, k = i & 63;
        w2t[c * 68 + k] = loadF(W2, (size_t)k * OUTD + c, f32);
    }
    const int nl = t >> 4, l16 = t & 15;
    const int n = blockIdx.x * 16 + nl;      // < NN (grid exact)
    const float dn = dinv[n];
    uint2 u0 = h1v[n * 16 + l16];            // fits int: < 800016
    float a0 = bflo(u0.x), a1 = bfhi(u0.x), a2 = bflo(u0.y), a3 = bfhi(u0.y);
    float e0 = 0.f, e1 = 0.f, e2 = 0.f, e3 = 0.f;
    const int rs = row_start[n] + pp[n >> 8], c = cnt[n];
    for (int base = 0; base < c; base += 16) {
        int rem = c - base;
        int sv = (l16 < rem) ? (int)csr16[rs + base + l16] : ZR;
        uint2 b[8], d[8];
#pragma unroll
        for (int j = 0; j < 8; j++) {
            int s = __shfl(sv, j, 16);
            b[j] = h1v[(s << 4) | l16];
        }
#pragma unroll
        for (int j = 0; j < 8; j++) {
            int s = __shfl(sv, j + 8, 16);
            d[j] = h1v[(s << 4) | l16];
        }
#pragma unroll
        for (int j = 0; j < 8; j++) {
            a0 += bflo(b[j].x); a1 += bfhi(b[j].x);
            a2 += bflo(b[j].y); a3 += bfhi(b[j].y);
            e0 += bflo(d[j].x); e1 += bfhi(d[j].x);
            e2 += bflo(d[j].y); e3 += bfhi(d[j].y);
        }
    }
    int cb = 4 * l16;
    float g0 = fmaxf(dn * (a0 + e0) + loadF(b1, cb, f32), 0.f);
    float g1 = fmaxf(dn * (a1 + e1) + loadF(b1, cb + 1, f32), 0.f);
    float g2 = fmaxf(dn * (a2 + e2) + loadF(b1, cb + 2, f32), 0.f);
    float g3 = fmaxf(dn * (a3 + e3) + loadF(b1, cb + 3, f32), 0.f);
    *(float4*)(gbuf + nl * 68 + cb) = make_float4(g0, g1, g2, g3);
    if (l16 == 0) dns[nl] = dn;
    __syncthreads();
    for (int idx = t; idx < 16 * OUTD; idx += 256) {
        int node = idx / OUTD, col = idx % OUTD;
        const float4* gp = (const float4*)(gbuf + node * 68);
        const float4* wp = (const float4*)(w2t + col * 68);
        float o = 0.f;
#pragma unroll 4
        for (int k4 = 0; k4 < 16; k4++) {
            float4 a = gp[k4], b = wp[k4];
            o += a.x * b.x + a.y * b.y + a.z * b.z + a.w * b.w;
        }
        obuf[node][col] = o * dns[node];
    }
    __syncthreads();
    if (t < 160) {
        int node = t / 10, dw = t % 10;
        const float* op = obuf[node] + dw * 4;
        h2f[(blockIdx.x * 16 + node) * 16 + dw] =
            pack_fp8x4(op[0], op[1], op[2], op[3]);
    }
}

// ---- CSR gather layer 2 (fp8 h2, 1 line/row) + bias + log_softmax ----------
__global__ __launch_bounds__(256, 4) void k_gather2(const unsigned* __restrict__ h2f,
                                                 const float* __restrict__ dinv,
                                                 const int* __restrict__ row_start,
                                                 const int* __restrict__ pp,
                                                 const int* __restrict__ cnt,
                                                 const unsigned short* __restrict__ csr16,
                                                 const void* __restrict__ b2,
                                                 const int* __restrict__ flags,
                                                 void* __restrict__ out) {
    const bool f32 = flags[0] != 0;
    const int t = threadIdx.x;
    const int nl = t >> 4, l16 = t & 15;
    const int n = blockIdx.x * 16 + nl;      // < NN (grid exact)
    const bool act = l16 < 10;               // 10 dwords (40 fp8 cols) per row
    const float dn = dinv[n];
    const int lclamp = act ? l16 : 9;        // inactive lanes read lane-9 slot (discarded)
    float a0, a1, a2, a3;
    unpack_fp8x4(h2f[n * 16 + lclamp], a0, a1, a2, a3);   // self row
    float e0 = 0.f, e1 = 0.f, e2 = 0.f, e3 = 0.f;
    const int rs = row_start[n] + pp[n >> 8], c = cnt[n];
    for (int base = 0; base < c; base += 16) {
        int rem = c - base;
        int sv = (l16 < rem) ? (int)csr16[rs + base + l16] : ZR;
        unsigned b[8], d[8];
#pragma unroll
        for (int j = 0; j < 8; j++) {
            int s = __shfl(sv, j, 16);
            b[j] = h2f[(s << 4) + lclamp];
        }
#pragma unroll
        for (int j = 0; j < 8; j++) {
            int s = __shfl(sv, j + 8, 16);
            d[j] = h2f[(s << 4) + lclamp];
        }
#pragma unroll
        for (int j = 0; j < 8; j++) {
            float x0, x1, x2, x3, y0, y1, y2, y3;
            unpack_fp8x4(b[j], x0, x1, x2, x3);
            unpack_fp8x4(d[j], y0, y1, y2, y3);
            a0 += x0; a1 += x1; a2 += x2; a3 += x3;
            e0 += y0; e1 += y1; e2 += y2; e3 += y3;
        }
    }
    int cb = 4 * l16;
    float v0 = -3.0e38f, v1 = -3.0e38f, v2 = -3.0e38f, v3 = -3.0e38f;
    if (act) {
        v0 = dn * (a0 + e0) + loadF(b2, cb, f32);
        v1 = dn * (a1 + e1) + loadF(b2, cb + 1, f32);
        v2 = dn * (a2 + e2) + loadF(b2, cb + 2, f32);
        v3 = dn * (a3 + e3) + loadF(b2, cb + 3, f32);
    }
    float mx = fmaxf(fmaxf(v0, v1), fmaxf(v2, v3));
#pragma unroll
    for (int off = 8; off; off >>= 1) mx = fmaxf(mx, __shfl_xor(mx, off, 16));
    float ev = act ? expf(v0 - mx) + expf(v1 - mx) + expf(v2 - mx) + expf(v3 - mx) : 0.f;
#pragma unroll
    for (int off = 8; off; off >>= 1) ev += __shfl_xor(ev, off, 16);
    float lg = logf(ev);
    if (act) {
        float r0 = v0 - mx - lg, r1 = v1 - mx - lg;
        float r2 = v2 - mx - lg, r3 = v3 - mx - lg;
        if (f32) {
            *(float4*)((float*)out + (size_t)n * OUTD + cb) = make_float4(r0, r1, r2, r3);
        } else {
            ((uint2*)out)[(size_t)n * 10 + l16] = make_uint2(pack2bf(r0, r1), pack2bf(r2, r3));
        }
    }
}

extern "C" void kernel_launch(void* const* d_in, const int* in_sizes, int n_in,
                              void* d_out, int out_size, void* d_ws, size_t ws_size,
                              hipStream_t stream) {
    const void* x  = d_in[0];
    const int*  ei = (const int*)d_in[1];
    const void* W1 = d_in[2];
    const void* b1 = d_in[3];
    const void* W2 = d_in[4];
    const void* b2 = d_in[5];

    // ws layout (4-byte words):
    // flags[16] | dinv[50048] | cnt[50048] | row_start[50048] | partial[256] |
    // pp[256] | rank8 uchar[800000] (200000 words) | csr16 ushort[800000] |
    // h1' bf16 [NNP*64] | h2' fp8 [NNP*16 dwords]   (~12.7 MB)
    float* ws        = (float*)d_ws;
    int*   flags     = (int*)ws;
    float* dinv      = ws + 16;
    int*   cnt       = (int*)(dinv + 50048);
    int*   row_start = cnt + 50048;
    int*   partial   = row_start + 50048;
    int*   pp        = partial + 256;
    unsigned char* rank8 = (unsigned char*)(pp + 256);        // 800000 B
    unsigned short* csr16 = (unsigned short*)(pp + 256 + 200000);
    unsigned short* h1u   = csr16 + NE;
    unsigned* h2f   = (unsigned*)(h1u + (size_t)NNP * HID);   // [NNP][16] dwords
    unsigned* h2pad = h2f + (size_t)ZR * 16;                  // 16 dwords

    k_zero  <<<(NN + 255) / 256, 256, 0, stream>>>((const unsigned*)x, ei, flags, cnt, h2pad);
    k_hist  <<<(NE + 255) / 256, 256, 0, stream>>>(ei, flags, cnt, rank8);
    k_scan1 <<<NC, 256, 0, stream>>>(cnt, row_start, partial, dinv);
    k_build <<<NCH + GB, 256, 0, stream>>>(ei, flags, row_start, partial, pp, rank8, csr16,
                                           x, W1, dinv, h1u);
    k_gather1f<<<NN / 16, 256, 0, stream>>>((const uint2*)h1u, dinv, row_start, pp, cnt,
                                            rank8, csr16, W2, b1, flags, h2f);
    k_gather2<<<NN / 16, 256, 0, stream>>>(h2f, dinv, row_start, pp, cnt, csr16,
                                           b2, flags, d_out);
}

// Round 10
// 192.007 us; speedup vs baseline: 1.2828x; 1.0859x over previous
//
#include <hip/hip_runtime.h>
#include <hip/hip_bf16.h>

// GCN 2-layer: N=50000 nodes, E=800000 edges, 256 -> 64 (relu) -> 40 (log_softmax)
// Gather model (R0-R6): per-row-touch rate ~20k/us invariant -> parked (~82us).
// R9: cooperative mega-kernel FAILED (absmax=|ref| => kernel didn't run under
// graph capture). Reverted. R10: kill k_hist's 800k atomic-returns (~50us by
// ledger) with a two-level LDS counting sort:
//   k_bingemm: bin edges into 196 coarse buckets (dst>>8) via LDS atomics +
//              77k global segment-alloc atomics, || gemm-raw (f32 h1r);
//   k_rankscan: per-bucket LDS hist -> per-edge rank + cnt/dinv/row_start/
//               partial (bucket == scan chunk, one kernel);
//   k_fillscale: CSR place from binned records || h1 scale (bf16(h1r*dinv)).
// Gathers = R8 verbatim. 6 launches.

constexpr int NN   = 50000;
constexpr int NNP  = 50048;                 // padded row count (zero rows >= NN)
constexpr int ZR   = 50000;                 // zero-row index for padding lanes
constexpr int NE   = 800000;
constexpr int FEAT = 256;
constexpr int HID  = 64;
constexpr int OUTD = 40;
constexpr int NC   = (NN + 255) / 256;      // 196 scan chunks == buckets
constexpr int NBUK = NC;                    // 196 coarse buckets (dst>>8)
constexpr int MAXB = 4608;                  // bucket region cap (mean 4082, +8sigma)
constexpr int FCH  = 2048;                  // bin: edges per chunk
constexpr int NCH  = (NE + FCH - 1) / FCH;  // 391 chunks
constexpr int GB   = NNP / 64;              // 782 gemm blocks

typedef short bf16x8 __attribute__((ext_vector_type(8)));
typedef float f32x4  __attribute__((ext_vector_type(4)));
typedef float f32x2  __attribute__((ext_vector_type(2)));

__device__ __forceinline__ float b2f(__hip_bfloat16 v) { return __bfloat162float(v); }
__device__ __forceinline__ float bflo(unsigned u) { return __uint_as_float(u << 16); }
__device__ __forceinline__ float bfhi(unsigned u) { return __uint_as_float(u & 0xffff0000u); }
__device__ __forceinline__ unsigned short f2bu(float f) {
    __hip_bfloat16 h = __float2bfloat16(f);
    return *(unsigned short*)&h;
}
__device__ __forceinline__ unsigned pack2bf(float a, float b) {
    return (unsigned)f2bu(a) | ((unsigned)f2bu(b) << 16);
}
__device__ __forceinline__ float loadF(const void* p, int i, bool f32) {
    return f32 ? ((const float*)p)[i] : b2f(((const __hip_bfloat16*)p)[i]);
}
__device__ __forceinline__ int loadE(const int* ei, int e, int row, bool i64) {
    long long idx = (long long)row * NE + e;
    return i64 ? ei[2 * idx] : ei[idx];
}
__device__ __forceinline__ bf16x8 pack8(float4 a, float4 b) {
    bf16x8 r;
    r[0] = (short)f2bu(a.x); r[1] = (short)f2bu(a.y);
    r[2] = (short)f2bu(a.z); r[3] = (short)f2bu(a.w);
    r[4] = (short)f2bu(b.x); r[5] = (short)f2bu(b.y);
    r[6] = (short)f2bu(b.z); r[7] = (short)f2bu(b.w);
    return r;
}

// ---- fp8 e4m3 (OCP) pack/unpack: HW cvt if available, exact SW fallback ----
#if __has_builtin(__builtin_amdgcn_cvt_pk_f32_fp8) && __has_builtin(__builtin_amdgcn_cvt_pk_fp8_f32)
__device__ __forceinline__ void unpack_fp8x4(unsigned u, float& f0, float& f1,
                                             float& f2, float& f3) {
    f32x2 lo = __builtin_amdgcn_cvt_pk_f32_fp8((int)u, false);
    f32x2 hi = __builtin_amdgcn_cvt_pk_f32_fp8((int)u, true);
    f0 = lo[0]; f1 = lo[1]; f2 = hi[0]; f3 = hi[1];
}
__device__ __forceinline__ unsigned pack_fp8x4(float a, float b, float c, float d) {
    int v = 0;
    v = __builtin_amdgcn_cvt_pk_fp8_f32(a, b, v, false);
    v = __builtin_amdgcn_cvt_pk_fp8_f32(c, d, v, true);
    return (unsigned)v;
}
#else
__device__ __forceinline__ float dec8(unsigned b) {
    return __uint_as_float(((b & 0x80u) << 24) | ((b & 0x7fu) << 20)) * 0x1p120f;
}
__device__ __forceinline__ void unpack_fp8x4(unsigned u, float& f0, float& f1,
                                             float& f2, float& f3) {
    f0 = dec8(u & 0xff); f1 = dec8((u >> 8) & 0xff);
    f2 = dec8((u >> 16) & 0xff); f3 = dec8(u >> 24);
}
__device__ __forceinline__ unsigned enc8(float f) {
    float a = fabsf(f) * 0x1p-120f;
    unsigned ub = __float_as_uint(a);
    unsigned lsb = (ub >> 20) & 1u;
    ub += 0x7FFFFu + lsb;                       // RNE into 3-bit mantissa
    unsigned v = (ub >> 20) & 0x7fu;
    if (v > 0x7e) v = 0x7e;
    return v | ((__float_as_uint(f) >> 24) & 0x80u);
}
__device__ __forceinline__ unsigned pack_fp8x4(float a, float b, float c, float d) {
    return enc8(a) | (enc8(b) << 8) | (enc8(c) << 16) | (enc8(d) << 24);
}
#endif

// ---- zero cursors + dtype detection (wave-parallel) + h2 pad-row zero ------
__global__ __launch_bounds__(256) void k_zero(const unsigned* __restrict__ xw,
                                              const int* __restrict__ ew,
                                              int* flags, int* bcur,
                                              unsigned* __restrict__ h2pad) {
    const int t = threadIdx.x;
    bcur[t] = 0;                               // 256 cursors (196 used)
    if (t < 16) h2pad[t] = 0;                  // fp8 zero row
    if (t < 64) {
        int outliers = 0;
#pragma unroll
        for (int k = t; k < 256; k += 64) {
            int e = (xw[k] >> 7) & 0xFF;       // exponent of low bf16 half
            if (e < 100 || e > 140) outliers++;
        }
        int nz = 0;
        if (t < 32) nz = (ew[1 + 2 * t] != 0) ? 1 : 0;
#pragma unroll
        for (int off = 32; off; off >>= 1) {
            outliers += __shfl_down(outliers, off, 64);
            nz       += __shfl_down(nz, off, 64);
        }
        if (t == 0) {
            flags[0] = (outliers > 64) ? 1 : 0;
            flags[1] = (nz == 0) ? 1 : 0;
        }
    }
}

// ---- bin (blocks [0,NCH)) || gemm-raw (blocks [NCH,NCH+GB)) ----------------
// bin: LDS histogram over 196 buckets + per-edge local rank (LDS atomic),
// one global atomic per (block,bucket) segment alloc, scatter packed records
// (src | lo8<<16) into bucket regions. gemm: h1r = x @ W1 (f32, unscaled).
__global__ __launch_bounds__(256) void k_bingemm(const int* __restrict__ ei,
                                                 const int* __restrict__ flags,
                                                 int* __restrict__ bcur,
                                                 unsigned* __restrict__ binned,
                                                 const void* __restrict__ xb,
                                                 const void* __restrict__ W1,
                                                 float* __restrict__ h1r) {
    __shared__ __align__(16) unsigned char smem[64 * 264 * 2];   // 33792 B union
    const bool f32 = flags[0] != 0;
    const int t = threadIdx.x;

    if (blockIdx.x < NCH) {
        const bool i64 = flags[1] != 0;
        int* histL = (int*)smem;               // [256]
        int* baseL = histL + 256;              // [256]
        histL[t] = 0;
        __syncthreads();
        int dk[8], sk[8], lk[8];
        const int e0 = blockIdx.x * FCH;
#pragma unroll
        for (int k = 0; k < 8; k++) {
            int e = e0 + k * 256 + t;
            if (e < NE) {
                dk[k] = loadE(ei, e, 1, i64);
                sk[k] = loadE(ei, e, 0, i64);
                lk[k] = atomicAdd(&histL[dk[k] >> 8], 1);
            } else {
                dk[k] = -1;
            }
        }
        __syncthreads();
        int hv = histL[t];
        baseL[t] = (hv > 0) ? atomicAdd(&bcur[t], hv) : 0;
        __syncthreads();
#pragma unroll
        for (int k = 0; k < 8; k++) {
            if (dk[k] >= 0) {
                int b = dk[k] >> 8;
                int off = baseL[b] + lk[k];
                if (off < MAXB)
                    binned[b * MAXB + off] = (unsigned)(sk[k] | ((dk[k] & 0xff) << 16));
            }
        }
        return;
    }

    // ---------------- gemm role (raw f32 output) ----------------
    const int bid = blockIdx.x - NCH;          // 0..GB-1
    unsigned short* wt16 = (unsigned short*)smem;
    if (f32) {
        const float* wf = (const float*)W1;
        for (int i = t * 4; i < FEAT * HID; i += 1024) {
            float4 w = *(const float4*)(wf + i);
            int k = i >> 6, n0 = i & 63;
            wt16[(n0 + 0) * 264 + k] = f2bu(w.x);
            wt16[(n0 + 1) * 264 + k] = f2bu(w.y);
            wt16[(n0 + 2) * 264 + k] = f2bu(w.z);
            wt16[(n0 + 3) * 264 + k] = f2bu(w.w);
        }
    } else {
        const unsigned short* wu = (const unsigned short*)W1;
        for (int i = t * 4; i < FEAT * HID; i += 1024) {
            ushort4 w = *(const ushort4*)(wu + i);
            int k = i >> 6, n0 = i & 63;
            wt16[(n0 + 0) * 264 + k] = w.x;
            wt16[(n0 + 1) * 264 + k] = w.y;
            wt16[(n0 + 2) * 264 + k] = w.z;
            wt16[(n0 + 3) * 264 + k] = w.w;
        }
    }
    const int wv = t >> 6, lane = t & 63, l15 = lane & 15, quad = lane >> 4;
    const int gr = bid * 64 + wv * 16 + l15;
    const bool rowok = gr < NN;
    f32x4 acc[4];
#pragma unroll
    for (int nt = 0; nt < 4; nt++) acc[nt] = (f32x4){0.f, 0.f, 0.f, 0.f};
    __syncthreads();

    if (f32) {
        const float* xr = (const float*)xb + (size_t)gr * FEAT + quad * 8;
        float4 z4 = make_float4(0, 0, 0, 0);
        float4 c0 = rowok ? *(const float4*)xr : z4;
        float4 c1 = rowok ? *(const float4*)(xr + 4) : z4;
#pragma unroll
        for (int ks = 0; ks < 8; ks++) {
            float4 n0 = z4, n1 = z4;
            if (ks < 7 && rowok) {
                n0 = *(const float4*)(xr + (ks + 1) * 32);
                n1 = *(const float4*)(xr + (ks + 1) * 32 + 4);
            }
            bf16x8 a = pack8(c0, c1);
            const unsigned short* wk = wt16 + ks * 32 + quad * 8;
#pragma unroll
            for (int nt = 0; nt < 4; nt++) {
                bf16x8 b = *(const bf16x8*)(wk + (size_t)(nt * 16 + l15) * 264);
                acc[nt] = __builtin_amdgcn_mfma_f32_16x16x32_bf16(a, b, acc[nt], 0, 0, 0);
            }
            c0 = n0; c1 = n1;
        }
    } else {
        const unsigned short* xr = (const unsigned short*)xb + (size_t)gr * FEAT + quad * 8;
        bf16x8 zz = (bf16x8){0, 0, 0, 0, 0, 0, 0, 0};
        bf16x8 cur = rowok ? *(const bf16x8*)xr : zz;
#pragma unroll
        for (int ks = 0; ks < 8; ks++) {
            bf16x8 nxt = zz;
            if (ks < 7 && rowok) nxt = *(const bf16x8*)(xr + (ks + 1) * 32);
            const unsigned short* wk = wt16 + ks * 32 + quad * 8;
#pragma unroll
            for (int nt = 0; nt < 4; nt++) {
                bf16x8 b = *(const bf16x8*)(wk + (size_t)(nt * 16 + l15) * 264);
                acc[nt] = __builtin_amdgcn_mfma_f32_16x16x32_bf16(cur, b, acc[nt], 0, 0, 0);
            }
            cur = nxt;
        }
    }
    const int rbase = bid * 64 + wv * 16 + quad * 4;
#pragma unroll
    for (int r = 0; r < 4; r++) {
        int grow = rbase + r;   // < NNP always
#pragma unroll
        for (int nt = 0; nt < 4; nt++)
            h1r[(size_t)grow * HID + nt * 16 + l15] = acc[nt][r];
    }
}

// ---- per-bucket rank (LDS) + cnt/dinv + scan1 (bucket == scan chunk) -------
__global__ __launch_bounds__(256) void k_rankscan(const int* __restrict__ bcur,
                                                  const unsigned* __restrict__ binned,
                                                  unsigned char* __restrict__ rank8b,
                                                  int* __restrict__ cnt,
                                                  float* __restrict__ dinv,
                                                  int* __restrict__ row_start,
                                                  int* __restrict__ partial) {
    __shared__ int h[256];
    __shared__ int s[256];
    const int t = threadIdx.x, b = blockIdx.x;
    h[t] = 0;
    __syncthreads();
    const int cntb = min(bcur[b], MAXB);
    const int base = b * MAXB;
    for (int pos = t; pos < cntb; pos += 256) {
        unsigned rec = binned[base + pos];
        int lo = (rec >> 16) & 0xff;
        rank8b[base + pos] = (unsigned char)atomicAdd(&h[lo], 1);
    }
    __syncthreads();
    const int i = b * 256 + t;
    int v = (i < NN) ? h[t] : 0;
    if (i < NN) {
        cnt[i] = v;
        dinv[i] = rsqrtf(1.0f + (float)v);     // +1 self loop
    }
    s[t] = v;
    __syncthreads();
    for (int off = 1; off < 256; off <<= 1) {
        int tmp = (t >= off) ? s[t - off] : 0;
        __syncthreads();
        s[t] += tmp;
        __syncthreads();
    }
    if (i < NN) row_start[i] = s[t] - v;       // exclusive within chunk
    if (t == 255) partial[b] = s[255];
}

// ---- fill from binned records (blocks [0,NBUK)) || h1 scale ([NBUK,+128)) --
__global__ __launch_bounds__(256) void k_fillscale(const int* __restrict__ flags,
                                                   const int* __restrict__ partial,
                                                   int* __restrict__ pp,
                                                   const int* __restrict__ row_start,
                                                   const int* __restrict__ bcur,
                                                   const unsigned* __restrict__ binned,
                                                   const unsigned char* __restrict__ rank8b,
                                                   unsigned short* __restrict__ csr16,
                                                   const float* __restrict__ h1r,
                                                   const float* __restrict__ dinv,
                                                   unsigned short* __restrict__ h1u) {
    const int t = threadIdx.x;
    if (blockIdx.x < NBUK) {
        __shared__ int ppL[256];
        int v = (t < NC) ? partial[t] : 0;
        ppL[t] = v;
        __syncthreads();
        for (int off = 1; off < 256; off <<= 1) {
            int tmp = (t >= off) ? ppL[t - off] : 0;
            __syncthreads();
            ppL[t] += tmp;
            __syncthreads();
        }
        int excl = ppL[t] - v;
        __syncthreads();
        ppL[t] = excl;
        __syncthreads();
        if (blockIdx.x == 0) pp[t] = excl;     // publish for gathers
        const int b = blockIdx.x;
        const int cntb = min(bcur[b], MAXB);
        const int base = b * MAXB;
        const int ppb = ppL[b];                // bucket b == scan chunk b
        for (int pos = t; pos < cntb; pos += 256) {
            unsigned rec = binned[base + pos];
            int sn = rec & 0xffff;
            int dn = (b << 8) | ((rec >> 16) & 0xff);
            int r = rank8b[base + pos];
            csr16[row_start[dn] + ppb + r] = (unsigned short)sn;
        }
    } else {
        const int sb2 = blockIdx.x - NBUK;     // 0..127
        for (int i = sb2 * 256 + t; i < NNP * 16; i += 128 * 256) {
            float4 vv = *(const float4*)(h1r + (size_t)i * 4);
            int row = i >> 4;
            float dv = (row < NN) ? dinv[row] : 0.f;
            ushort4 o;
            o.x = f2bu(vv.x * dv); o.y = f2bu(vv.y * dv);
            o.z = f2bu(vv.z * dv); o.w = f2bu(vv.w * dv);
            *(ushort4*)(h1u + (size_t)i * 4) = o;
        }
    }
}

// ---- fused: s = sum h1'[{n}uN(n)] ; g = relu(dn*s + b1) ; h2' = dn*(g@W2) --
// R8 verbatim. h2 OUTPUT fp8 e4m3, 16-dword rows.
__global__ __launch_bounds__(256, 4) void k_gather1f(const uint2* __restrict__ h1v,
                                                  const float* __restrict__ dinv,
                                                  const int* __restrict__ row_start,
                                                  const int* __restrict__ pp,
                                                  const int* __restrict__ cnt,
                                                  const unsigned short* __restrict__ csr16,
                                                  const void* __restrict__ W2,
                                                  const void* __restrict__ b1,
                                                  const int* __restrict__ flags,
                                                  unsigned* __restrict__ h2f) {
    __shared__ __align__(16) float w2t[OUTD * 68];   // [col][k], stride 68
    __shared__ __align__(16) float gbuf[16 * 68];    // [node][k], stride 68
    __shared__ __align__(16) float obuf[16][40];     // [node][col] f32 pre-pack
    __shared__ float dns[16];
    const bool f32 = flags[0] != 0;
    const int t = threadIdx.x;
    for (int i = t; i < HID * OUTD; i += 256) {
        int c = i >> 6, k = i & 63;
        w2t[c * 68 + k] = loadF(W2, (size_t)k * OUTD + c, f32);
    }
    const int nl = t >> 4, l16 = t & 15;
    const int n = blockIdx.x * 16 + nl;      // < NN (grid exact)
    const float dn = dinv[n];
    uint2 u0 = h1v[n * 16 + l16];            // fits int: < 800016
    float a0 = bflo(u0.x), a1 = bfhi(u0.x), a2 = bflo(u0.y), a3 = bfhi(u0.y);
    float e0 = 0.f, e1 = 0.f, e2 = 0.f, e3 = 0.f;
    const int rs = row_start[n] + pp[n >> 8], c = cnt[n];
    for (int base = 0; base < c; base += 16) {
        int rem = c - base;
        int sv = (l16 < rem) ? (int)csr16[rs + base + l16] : ZR;
        uint2 b[8], d[8];
#pragma unroll
        for (int j = 0; j < 8; j++) {
            int s = __shfl(sv, j, 16);
            b[j] = h1v[(s << 4) | l16];
        }
#pragma unroll
        for (int j = 0; j < 8; j++) {
            int s = __shfl(sv, j + 8, 16);
            d[j] = h1v[(s << 4) | l16];
        }
#pragma unroll
        for (int j = 0; j < 8; j++) {
            a0 += bflo(b[j].x); a1 += bfhi(b[j].x);
            a2 += bflo(b[j].y); a3 += bfhi(b[j].y);
            e0 += bflo(d[j].x); e1 += bfhi(d[j].x);
            e2 += bflo(d[j].y); e3 += bfhi(d[j].y);
        }
    }
    int cb = 4 * l16;
    float g0 = fmaxf(dn * (a0 + e0) + loadF(b1, cb, f32), 0.f);
    float g1 = fmaxf(dn * (a1 + e1) + loadF(b1, cb + 1, f32), 0.f);
    float g2 = fmaxf(dn * (a2 + e2) + loadF(b1, cb + 2, f32), 0.f);
    float g3 = fmaxf(dn * (a3 + e3) + loadF(b1, cb + 3, f32), 0.f);
    *(float4*)(gbuf + nl * 68 + cb) = make_float4(g0, g1, g2, g3);
    if (l16 == 0) dns[nl] = dn;
    __syncthreads();
    for (int idx = t; idx < 16 * OUTD; idx += 256) {
        int node = idx / OUTD, col = idx % OUTD;
        const float4* gp = (const float4*)(gbuf + node * 68);
        const float4* wp = (const float4*)(w2t + col * 68);
        float o = 0.f;
#pragma unroll 4
        for (int k4 = 0; k4 < 16; k4++) {
            float4 a = gp[k4], b = wp[k4];
            o += a.x * b.x + a.y * b.y + a.z * b.z + a.w * b.w;
        }
        obuf[node][col] = o * dns[node];
    }
    __syncthreads();
    if (t < 160) {
        int node = t / 10, dw = t % 10;
        const float* op = obuf[node] + dw * 4;
        h2f[(blockIdx.x * 16 + node) * 16 + dw] =
            pack_fp8x4(op[0], op[1], op[2], op[3]);
    }
}

// ---- CSR gather layer 2 (fp8 h2, 1 line/row) + bias + log_softmax ----------
// R8 verbatim.
__global__ __launch_bounds__(256, 4) void k_gather2(const unsigned* __restrict__ h2f,
                                                 const float* __restrict__ dinv,
                                                 const int* __restrict__ row_start,
                                                 const int* __restrict__ pp,
                                                 const int* __restrict__ cnt,
                                                 const unsigned short* __restrict__ csr16,
                                                 const void* __restrict__ b2,
                                                 const int* __restrict__ flags,
                                                 void* __restrict__ out) {
    const bool f32 = flags[0] != 0;
    const int t = threadIdx.x;
    const int nl = t >> 4, l16 = t & 15;
    const int n = blockIdx.x * 16 + nl;      // < NN (grid exact)
    const bool act = l16 < 10;               // 10 dwords (40 fp8 cols) per row
    const float dn = dinv[n];
    const int lclamp = act ? l16 : 9;        // inactive lanes read lane-9 slot (discarded)
    float a0, a1, a2, a3;
    unpack_fp8x4(h2f[n * 16 + lclamp], a0, a1, a2, a3);   // self row
    float e0 = 0.f, e1 = 0.f, e2 = 0.f, e3 = 0.f;
    const int rs = row_start[n] + pp[n >> 8], c = cnt[n];
    for (int base = 0; base < c; base += 16) {
        int rem = c - base;
        int sv = (l16 < rem) ? (int)csr16[rs + base + l16] : ZR;
        unsigned b[8], d[8];
#pragma unroll
        for (int j = 0; j < 8; j++) {
            int s = __shfl(sv, j, 16);
            b[j] = h2f[(s << 4) + lclamp];
        }
#pragma unroll
        for (int j = 0; j < 8; j++) {
            int s = __shfl(sv, j + 8, 16);
            d[j] = h2f[(s << 4) + lclamp];
        }
#pragma unroll
        for (int j = 0; j < 8; j++) {
            float x0, x1, x2, x3, y0, y1, y2, y3;
            unpack_fp8x4(b[j], x0, x1, x2, x3);
            unpack_fp8x4(d[j], y0, y1, y2, y3);
            a0 += x0; a1 += x1; a2 += x2; a3 += x3;
            e0 += y0; e1 += y1; e2 += y2; e3 += y3;
        }
    }
    int cb = 4 * l16;
    float v0 = -3.0e38f, v1 = -3.0e38f, v2 = -3.0e38f, v3 = -3.0e38f;
    if (act) {
        v0 = dn * (a0 + e0) + loadF(b2, cb, f32);
        v1 = dn * (a1 + e1) + loadF(b2, cb + 1, f32);
        v2 = dn * (a2 + e2) + loadF(b2, cb + 2, f32);
        v3 = dn * (a3 + e3) + loadF(b2, cb + 3, f32);
    }
    float mx = fmaxf(fmaxf(v0, v1), fmaxf(v2, v3));
#pragma unroll
    for (int off = 8; off; off >>= 1) mx = fmaxf(mx, __shfl_xor(mx, off, 16));
    float ev = act ? expf(v0 - mx) + expf(v1 - mx) + expf(v2 - mx) + expf(v3 - mx) : 0.f;
#pragma unroll
    for (int off = 8; off; off >>= 1) ev += __shfl_xor(ev, off, 16);
    float lg = logf(ev);
    if (act) {
        float r0 = v0 - mx - lg, r1 = v1 - mx - lg;
        float r2 = v2 - mx - lg, r3 = v3 - mx - lg;
        if (f32) {
            *(float4*)((float*)out + (size_t)n * OUTD + cb) = make_float4(r0, r1, r2, r3);
        } else {
            ((uint2*)out)[(size_t)n * 10 + l16] = make_uint2(pack2bf(r0, r1), pack2bf(r2, r3));
        }
    }
}

extern "C" void kernel_launch(void* const* d_in, const int* in_sizes, int n_in,
                              void* d_out, int out_size, void* d_ws, size_t ws_size,
                              hipStream_t stream) {
    const void* x  = d_in[0];
    const int*  ei = (const int*)d_in[1];
    const void* W1 = d_in[2];
    const void* b1 = d_in[3];
    const void* W2 = d_in[4];
    const void* b2 = d_in[5];

    // ws layout (4-byte words):
    // flags[16] | dinv[50048] | cnt[50048] | row_start[50048] | partial[256] |
    // pp[256] | bcur[256] | binned uint[196*4608] | rank8b uchar[196*4608] |
    // csr16 ushort[800000] | h1u bf16[NNP*64] | h2f uint[NNP*16] |
    // h1r f32[NNP*64]   (~30 MB)
    float* ws        = (float*)d_ws;
    int*   flags     = (int*)ws;
    float* dinv      = ws + 16;
    int*   cnt       = (int*)(dinv + 50048);
    int*   row_start = cnt + 50048;
    int*   partial   = row_start + 50048;
    int*   pp        = partial + 256;
    int*   bcur      = pp + 256;                                  // 256
    unsigned* binned = (unsigned*)(bcur + 256);                   // 196*4608
    unsigned char* rank8b = (unsigned char*)(binned + NBUK * MAXB);   // 903168 B
    unsigned short* csr16 = (unsigned short*)(rank8b + NBUK * MAXB);
    unsigned short* h1u   = csr16 + NE;                           // NNP*64 bf16
    unsigned* h2f = (unsigned*)(h1u + (size_t)NNP * HID);         // NNP*16 dw
    float* h1r    = (float*)(h2f + (size_t)NNP * 16);             // NNP*64 f32
    unsigned* h2pad = h2f + (size_t)ZR * 16;                      // 16 dwords

    k_zero   <<<1, 256, 0, stream>>>((const unsigned*)x, ei, flags, bcur, h2pad);
    k_bingemm<<<NCH + GB, 256, 0, stream>>>(ei, flags, bcur, binned, x, W1, h1r);
    k_rankscan<<<NBUK, 256, 0, stream>>>(bcur, binned, rank8b, cnt, dinv, row_start, partial);
    k_fillscale<<<NBUK + 128, 256, 0, stream>>>(flags, partial, pp, row_start, bcur, binned,
                                                rank8b, csr16, h1r, dinv, h1u);
    k_gather1f<<<NN / 16, 256, 0, stream>>>((const uint2*)h1u, dinv, row_start, pp, cnt,
                                            csr16, W2, b1, flags, h2f);
    k_gather2<<<NN / 16, 256, 0, stream>>>(h2f, dinv, row_start, pp, cnt, csr16,
                                           b2, flags, d_out);
}